// Round 8
// baseline (1982.342 us; speedup 1.0000x reference)
//
#include <hip/hip_runtime.h>
#include <hip/hip_bf16.h>

// Problem constants (fixed by setup_inputs)
constexpr int    TOT = 65536;        // nodes per side
constexpr int    TOT2 = 131072;      // both sides
constexpr long long Ec = 16LL * TOT; // 1048576 edges per side
constexpr int    NB  = 1024;         // dst buckets (128 nodes each)
constexpr int    BKN = 128;          // nodes per bucket

typedef unsigned int   uint32;
typedef unsigned short ushort16;
typedef __attribute__((ext_vector_type(8))) short bf16x8;
typedef __attribute__((ext_vector_type(4))) float f32x4;

__device__ __forceinline__ float sigm(float x) { return 1.f / (1.f + __expf(-x)); }

__device__ __forceinline__ uint32 f2bf_rne(float x) {
    uint32 u = __float_as_uint(x);
    return (u + 0x7fffu + ((u >> 16) & 1u)) >> 16;
}
__device__ __forceinline__ float2 bf2f(uint32 u) {
    return make_float2(__uint_as_float(u << 16), __uint_as_float(u & 0xffff0000u));
}
__device__ __forceinline__ float bf1f(ushort16 u) {
    return __uint_as_float(((uint32)u) << 16);
}

// ---------------- batch segments via binary search (sorted batch arrays) ----------------
__global__ void bs_k(const int* __restrict__ b1, const int* __restrict__ b2,
                     int* __restrict__ cnt, int* __restrict__ st) {
    int t = threadIdx.x;
    const int* bat = (t < 128) ? b1 : b2;
    const int g = t & 127;
    int lo = 0, hi = TOT;
    while (lo < hi) { int m = (lo + hi) >> 1; if (bat[m] < g) lo = m + 1; else hi = m; }
    const int s0 = lo;
    hi = TOT;
    while (lo < hi) { int m = (lo + hi) >> 1; if (bat[m] < g + 1) lo = m + 1; else hi = m; }
    st[t] = s0;
    cnt[t] = lo - s0;
}

// ---------------- edge bucketing: pass A (count + reserve) ----------------
// 256 blocks x 8192 edges. Bucket = global dst node >> 7.
__global__ __launch_bounds__(256) void bktcnt_k(const int* __restrict__ ei1, const int* __restrict__ ei2,
                                                int* __restrict__ gcnt, int* __restrict__ blkbase) {
    __shared__ int hist[NB];
    const int tid = threadIdx.x, blk = blockIdx.x;
#pragma unroll
    for (int q = 0; q < 4; ++q) hist[q * 256 + tid] = 0;
    __syncthreads();
    const long long base = (long long)blk * 8192;
    for (int q = 0; q < 32; ++q) {
        long long e = base + q * 256 + tid;
        int d = (e < Ec) ? ei1[Ec + e] : (TOT + ei2[Ec + (e - Ec)]);
        atomicAdd(&hist[d >> 7], 1);
    }
    __syncthreads();
#pragma unroll
    for (int q = 0; q < 4; ++q) {
        int bb = q * 256 + tid;
        int c = hist[bb];
        int old = atomicAdd(&gcnt[bb], c);
        blkbase[blk * NB + bb] = old;
    }
}

// ---------------- exclusive scan of 1024 bucket counts ----------------
__global__ __launch_bounds__(1024) void scan1024_k(const int* __restrict__ gcnt, int* __restrict__ goff) {
    __shared__ int ws[16];
    const int t = threadIdx.x, lane = t & 63, wid = t >> 6;
    int v = gcnt[t];
    int inc = v;
#pragma unroll
    for (int d = 1; d < 64; d <<= 1) { int n = __shfl_up(inc, d, 64); if (lane >= d) inc += n; }
    if (lane == 63) ws[wid] = inc;
    __syncthreads();
    if (t == 0) { int o = 0; for (int q = 0; q < 16; ++q) { int x = ws[q]; ws[q] = o; o += x; } }
    __syncthreads();
    goff[t] = ws[wid] + inc - v;
    if (t == 1023) goff[NB] = ws[15] + inc;
}

// ---------------- edge bucketing: pass C (scatter into per-block runs) ----------------
// payload: src_global (17b) | dst_local (7b) << 20
__global__ __launch_bounds__(256) void bktfill_k(const int* __restrict__ ei1, const int* __restrict__ ei2,
                                                 const int* __restrict__ goff, const int* __restrict__ blkbase,
                                                 uint32* __restrict__ bkt) {
    __shared__ int hist[NB];
    __shared__ int hbase[NB];
    const int tid = threadIdx.x, blk = blockIdx.x;
#pragma unroll
    for (int q = 0; q < 4; ++q) {
        int bb = q * 256 + tid;
        hist[bb] = 0;
        hbase[bb] = goff[bb] + blkbase[blk * NB + bb];
    }
    __syncthreads();
    const long long base = (long long)blk * 8192;
    for (int q = 0; q < 32; ++q) {
        long long e = base + q * 256 + tid;
        int s, d;
        if (e < Ec) { s = ei1[e]; d = ei1[Ec + e]; }
        else        { long long e2 = e - Ec; s = TOT + ei2[e2]; d = TOT + ei2[Ec + e2]; }
        int bb = d >> 7;
        int lofs = atomicAdd(&hist[bb], 1);
        bkt[hbase[bb] + lofs] = (uint32)s | ((uint32)(d & 127) << 20);
    }
}

// ---------------- per-bucket degree -> dis ----------------
__global__ __launch_bounds__(256) void degdis_k(const int* __restrict__ goff, const uint32* __restrict__ bkt,
                                                float* __restrict__ dis) {
    __shared__ int deg[BKN];
    const int b = blockIdx.x, tid = threadIdx.x;
    if (tid < BKN) deg[tid] = 0;
    __syncthreads();
    const int e0 = goff[b], e1 = goff[b + 1];
    for (int e = e0 + tid; e < e1; e += 256) atomicAdd(&deg[bkt[e] >> 20], 1);
    __syncthreads();
    if (tid < BKN) dis[b * BKN + tid] = rsqrtf((float)deg[tid] + 1.0f);
}

// ---------------- GEMM: out_bf16[M,NC] = dis[row] * ((relu?)X[M,K] @ W[K,NC]) ----------------
template<int K, int NC, bool RELU, bool XBF>
__global__ __launch_bounds__(256) void gemm_k(const void* __restrict__ X1v,
                                              const void* __restrict__ X2v,
                                              const float* __restrict__ W,
                                              const float* __restrict__ dis,
                                              uint32* __restrict__ out) {
    __shared__ float Ws[K * NC];
    const int tid = threadIdx.x;
    constexpr int WE4 = K * NC / 1024;
    {
        const float4* Wg = (const float4*)W;
        float4* Wp = (float4*)Ws;
#pragma unroll
        for (int it = 0; it < WE4; ++it) Wp[tid + it * 256] = Wg[tid + it * 256];
    }
    __syncthreads();
    const size_t row = (size_t)blockIdx.x * 256 + tid;
    float acc[NC];
#pragma unroll
    for (int j = 0; j < NC; ++j) acc[j] = 0.f;

    if (XBF) {
        const uint32* Xb = (row < TOT) ? (const uint32*)X1v + row * (K / 2)
                                       : (const uint32*)X2v + (row - TOT) * (K / 2);
        const uint4* Xr = (const uint4*)Xb;
#pragma unroll 2
        for (int k8 = 0; k8 < K / 8; ++k8) {
            uint4 xv = Xr[k8];
            float2 p0 = bf2f(xv.x), p1 = bf2f(xv.y), p2 = bf2f(xv.z), p3 = bf2f(xv.w);
            float xs[8] = {p0.x, p0.y, p1.x, p1.y, p2.x, p2.y, p3.x, p3.y};
            if (RELU) {
#pragma unroll
                for (int q = 0; q < 8; ++q) xs[q] = fmaxf(xs[q], 0.f);
            }
#pragma unroll
            for (int kk = 0; kk < 8; ++kk) {
#pragma unroll
                for (int j4 = 0; j4 < NC / 4; ++j4) {
                    float4 wv = *(const float4*)&Ws[(k8 * 8 + kk) * NC + j4 * 4];
                    acc[j4 * 4 + 0] += xs[kk] * wv.x;
                    acc[j4 * 4 + 1] += xs[kk] * wv.y;
                    acc[j4 * 4 + 2] += xs[kk] * wv.z;
                    acc[j4 * 4 + 3] += xs[kk] * wv.w;
                }
            }
        }
    } else {
        const float4* Xr = (row < TOT) ? (const float4*)((const float*)X1v + row * K)
                                       : (const float4*)((const float*)X2v + (row - TOT) * K);
#pragma unroll 2
        for (int k4 = 0; k4 < K / 4; ++k4) {
            float4 xv = Xr[k4];
            if (RELU) {
                xv.x = fmaxf(xv.x, 0.f); xv.y = fmaxf(xv.y, 0.f);
                xv.z = fmaxf(xv.z, 0.f); xv.w = fmaxf(xv.w, 0.f);
            }
            const float xs[4] = {xv.x, xv.y, xv.z, xv.w};
#pragma unroll
            for (int kk = 0; kk < 4; ++kk) {
#pragma unroll
                for (int j4 = 0; j4 < NC / 4; ++j4) {
                    float4 wv = *(const float4*)&Ws[(k4 * 4 + kk) * NC + j4 * 4];
                    acc[j4 * 4 + 0] += xs[kk] * wv.x;
                    acc[j4 * 4 + 1] += xs[kk] * wv.y;
                    acc[j4 * 4 + 2] += xs[kk] * wv.z;
                    acc[j4 * 4 + 3] += xs[kk] * wv.w;
                }
            }
        }
    }
    const float disv = dis[row];
    uint4* O4 = (uint4*)(out + row * (NC / 2));
#pragma unroll
    for (int j8 = 0; j8 < NC / 8; ++j8) {
        uint4 v;
        v.x = f2bf_rne(acc[j8 * 8 + 0] * disv) | (f2bf_rne(acc[j8 * 8 + 1] * disv) << 16);
        v.y = f2bf_rne(acc[j8 * 8 + 2] * disv) | (f2bf_rne(acc[j8 * 8 + 3] * disv) << 16);
        v.z = f2bf_rne(acc[j8 * 8 + 4] * disv) | (f2bf_rne(acc[j8 * 8 + 5] * disv) << 16);
        v.w = f2bf_rne(acc[j8 * 8 + 6] * disv) | (f2bf_rne(acc[j8 * 8 + 7] * disv) << 16);
        O4[j8] = v;
    }
}

// ---------------- aggregation: one block per bucket, LDS f32 accumulators ----------------
// out_bf16[i] = dis[i] * (hs[i] + sum_{e->i} hs[src]) + bias
template<int NC>
__global__ __launch_bounds__(256) void agg_k(uint32* __restrict__ out, const uint32* __restrict__ hs,
                                             const float* __restrict__ dis, const float* __restrict__ bias,
                                             const int* __restrict__ goff, const uint32* __restrict__ bkt) {
    constexpr int NU = NC / 2;         // u32 per row
    __shared__ float acc[BKN * NC];
    const int b = blockIdx.x, tid = threadIdx.x;
    const int node0 = b * BKN;
    // init with self term
    for (int q = tid; q < BKN * NU; q += 256) {
        float2 f = bf2f(hs[(size_t)node0 * NU + q]);
        acc[q * 2] = f.x;
        acc[q * 2 + 1] = f.y;
    }
    __syncthreads();
    const int e0 = goff[b], e1 = goff[b + 1];
    const int grp = tid >> 4;          // 16 groups of 16 lanes
    const int l = tid & 15;
    for (int e = e0 + grp; e < e1; e += 16) {
        uint32 v = bkt[e];
        int src = v & 0x1FFFF;
        int dl = v >> 20;
        if (NU == 32) {
            uint2 p = *(const uint2*)&hs[(size_t)src * 32 + l * 2];
            float2 f0 = bf2f(p.x), f1 = bf2f(p.y);
            atomicAdd(&acc[dl * NC + 4 * l + 0], f0.x);
            atomicAdd(&acc[dl * NC + 4 * l + 1], f0.y);
            atomicAdd(&acc[dl * NC + 4 * l + 2], f1.x);
            atomicAdd(&acc[dl * NC + 4 * l + 3], f1.y);
        } else {
            uint32 p = hs[(size_t)src * NU + l];
            float2 f = bf2f(p);
            atomicAdd(&acc[dl * NC + 2 * l + 0], f.x);
            atomicAdd(&acc[dl * NC + 2 * l + 1], f.y);
        }
    }
    __syncthreads();
    const float2* bias2 = (const float2*)bias;
    for (int q = tid; q < BKN * NU; q += 256) {
        int n = q / NU, u = q - n * NU;
        float dv = dis[node0 + n];
        float2 bb = bias2[u];
        float o0 = acc[n * NC + 2 * u] * dv + bb.x;
        float o1 = acc[n * NC + 2 * u + 1] * dv + bb.y;
        out[(size_t)node0 * NU + q] = f2bf_rne(o0) | (f2bf_rne(o1) << 16);
    }
}

// ---------------- attention pooling (bf16 AF input) ----------------
__global__ __launch_bounds__(256) void attpool_k(const ushort16* __restrict__ af,
                                                 const int* __restrict__ cnt, const int* __restrict__ st,
                                                 const float* __restrict__ attW, float* __restrict__ pool) {
    const int side = blockIdx.x >> 7, b = blockIdx.x & 127;
    const ushort16* h = af + (size_t)side * TOT * 32;
    const int c = cnt[side * 128 + b], s0 = st[side * 128 + b];
    const int f = threadIdx.x & 31, grp = threadIdx.x >> 5;
    __shared__ float red[8][32];
    __shared__ float mhS[32], tS[32];
    float acc = 0.f;
    for (int i = grp; i < c; i += 8) acc += bf1f(h[(size_t)(s0 + i) * 32 + f]);
    red[grp][f] = acc;
    __syncthreads();
    if (threadIdx.x < 32) { float tt = 0; for (int g = 0; g < 8; ++g) tt += red[g][f]; mhS[f] = tt / (float)c; }
    __syncthreads();
    if (threadIdx.x < 32) {
        float g = 0;
        for (int k = 0; k < 32; ++k) g += mhS[k] * attW[k * 32 + f];
        tS[f] = tanhf(g);
    }
    __syncthreads();
    const float tf = tS[f];
    acc = 0.f;
    for (int i = grp; i < c; i += 8) {
        float hv = bf1f(h[(size_t)(s0 + i) * 32 + f]);
        float pr = hv * tf;
#pragma unroll
        for (int m = 16; m; m >>= 1) pr += __shfl_xor(pr, m, 32);
        float sA = 1.f / (1.f + expf(-pr));
        acc += hv * sA;
    }
    __syncthreads();
    red[grp][f] = acc;
    __syncthreads();
    if (threadIdx.x < 32) {
        float tt = 0; for (int g = 0; g < 8; ++g) tt += red[g][f];
        pool[(size_t)(side * 128 + b) * 32 + f] = tt;
    }
}

// ---------------- histogram pass 1: MFMA min/max of raw dots ----------------
__global__ __launch_bounds__(256) void mm2_k(const ushort16* __restrict__ afb,
                                             const int* __restrict__ cnt, const int* __restrict__ st,
                                             float* __restrict__ bmn, float* __restrict__ bmx) {
    const int b = blockIdx.x >> 3, it8 = blockIdx.x & 7;
    const int c1 = cnt[b], c2 = cnt[128 + b];
    const int s1 = st[b], s2 = st[128 + b];
    const int nn = max(c1, c2);
    const int tid = threadIdx.x, lane = tid & 63, wave = tid >> 6;
    const int itile = it8 * 4 + wave;
    const int i0 = itile * 16;
    float lmn = 1e30f, lmx = -1e30f;
    if (i0 < nn) {
        const int arow = i0 + (lane & 15);
        const int koff = (lane >> 4) * 8;
        bf16x8 a = {0, 0, 0, 0, 0, 0, 0, 0};
        if (arow < c1) a = *(const bf16x8*)(afb + (size_t)(s1 + arow) * 32 + koff);
        const int ibase = i0 + (lane >> 4) * 4;
        const int njt = (nn + 15) >> 4;
        for (int jt = 0; jt < njt; ++jt) {
            const int brow = jt * 16 + (lane & 15);
            bf16x8 bb = {0, 0, 0, 0, 0, 0, 0, 0};
            if (brow < c2) bb = *(const bf16x8*)(afb + (size_t)(s2 + brow) * 32 + koff);
            f32x4 cc = {0.f, 0.f, 0.f, 0.f};
            cc = __builtin_amdgcn_mfma_f32_16x16x32_bf16(a, bb, cc, 0, 0, 0);
            if (brow < nn) {
#pragma unroll
                for (int r = 0; r < 4; ++r) {
                    if (ibase + r < nn) { lmn = fminf(lmn, cc[r]); lmx = fmaxf(lmx, cc[r]); }
                }
            }
        }
    }
    __shared__ float redn[256], redx[256];
    redn[tid] = lmn; redx[tid] = lmx;
    __syncthreads();
    for (int sr = 128; sr; sr >>= 1) {
        if (tid < sr) {
            redn[tid] = fminf(redn[tid], redn[tid + sr]);
            redx[tid] = fmaxf(redx[tid], redx[tid + sr]);
        }
        __syncthreads();
    }
    if (tid == 0) { bmn[blockIdx.x] = redn[0]; bmx[blockIdx.x] = redx[0]; }
}

// ---------------- histogram pass 2: MFMA + bin ----------------
__global__ __launch_bounds__(256) void bin2_k(const ushort16* __restrict__ afb,
                                              const int* __restrict__ cnt, const int* __restrict__ st,
                                              const float* __restrict__ bmn, const float* __restrict__ bmx,
                                              float* __restrict__ hist) {
    const int b = blockIdx.x >> 3, it8 = blockIdx.x & 7;
    const int c1 = cnt[b], c2 = cnt[128 + b];
    const int s1 = st[b], s2 = st[128 + b];
    const int nn = max(c1, c2);
    const int tid = threadIdx.x, lane = tid & 63, wave = tid >> 6;
    const int itile = it8 * 4 + wave;
    const int i0 = itile * 16;
    float dmn = 1e30f, dmx = -1e30f;
#pragma unroll
    for (int q = 0; q < 8; ++q) {
        dmn = fminf(dmn, bmn[(b << 3) + q]);
        dmx = fmaxf(dmx, bmx[(b << 3) + q]);
    }
    const float vMn = sigm(dmn), vMx = sigm(dmx);
    const float vScale = 16.f / ((vMx > vMn) ? (vMx - vMn) : 1.f);
    __shared__ int hloc[16 * 256];
    __shared__ int part[64];
#pragma unroll
    for (int q = 0; q < 16; ++q) hloc[q * 256 + tid] = 0;
    __syncthreads();
    if (i0 < nn) {
        const int arow = i0 + (lane & 15);
        const int koff = (lane >> 4) * 8;
        bf16x8 a = {0, 0, 0, 0, 0, 0, 0, 0};
        if (arow < c1) a = *(const bf16x8*)(afb + (size_t)(s1 + arow) * 32 + koff);
        const int ibase = i0 + (lane >> 4) * 4;
        const int njt = (nn + 15) >> 4;
        for (int jt = 0; jt < njt; ++jt) {
            const int brow = jt * 16 + (lane & 15);
            bf16x8 bb = {0, 0, 0, 0, 0, 0, 0, 0};
            if (brow < c2) bb = *(const bf16x8*)(afb + (size_t)(s2 + brow) * 32 + koff);
            f32x4 cc = {0.f, 0.f, 0.f, 0.f};
            cc = __builtin_amdgcn_mfma_f32_16x16x32_bf16(a, bb, cc, 0, 0, 0);
            if (brow < nn) {
#pragma unroll
                for (int r = 0; r < 4; ++r) {
                    if (ibase + r < nn) {
                        float t = (sigm(cc[r]) - vMn) * vScale;
                        int bi = (int)floorf(t);
                        bi = bi < 0 ? 0 : (bi > 15 ? 15 : bi);
                        hloc[bi * 256 + tid] += 1;
                    }
                }
            }
        }
    }
    __syncthreads();
    if (tid < 64) {
        const int bin = tid & 15, q = tid >> 4;
        int s = 0;
        for (int t2 = q * 64; t2 < q * 64 + 64; ++t2) s += hloc[bin * 256 + t2];
        part[tid] = s;
    }
    __syncthreads();
    if (tid < 16) {
        int s = part[tid] + part[16 + tid] + part[32 + tid] + part[48 + tid];
        atomicAdd(&hist[b * 16 + tid], (float)s);
    }
}

// ---------------- NTN + final MLP (one block per graph) ----------------
__global__ __launch_bounds__(64) void final_k(const float* __restrict__ pool, const float* __restrict__ hist,
                                              const int* __restrict__ cnt,
                                              const float* __restrict__ ntnW, const float* __restrict__ ntnV,
                                              const float* __restrict__ ntnb, const float* __restrict__ fc1W,
                                              const float* __restrict__ fc1b, const float* __restrict__ scW,
                                              const float* __restrict__ scb, float* __restrict__ out) {
    const int b = blockIdx.x;
    const int tid = threadIdx.x;
    __shared__ float P1[32], P2[32], feat[32], red[64];
    if (tid < 32) { P1[tid] = pool[b * 32 + tid]; P2[tid] = pool[4096 + b * 32 + tid]; }
    __syncthreads();
    const int k = tid & 15, part = tid >> 4;
    float acc = 0.f;
    for (int i = part * 8; i < part * 8 + 8; ++i) {
        float p1i = P1[i];
        for (int j = 0; j < 32; ++j) acc += p1i * P2[j] * ntnW[(i * 32 + j) * 16 + k];
    }
    red[tid] = acc;
    __syncthreads();
    if (tid < 16) {
        float bl = red[tid] + red[16 + tid] + red[32 + tid] + red[48 + tid];
        float blk = ntnb[tid];
        for (int i = 0; i < 32; ++i) blk += P1[i] * ntnV[tid * 64 + i];
        for (int j = 0; j < 32; ++j) blk += P2[j] * ntnV[tid * 64 + 32 + j];
        feat[tid] = fmaxf(bl + blk, 0.f);
        const int nn = max(cnt[b], cnt[128 + b]);
        feat[16 + tid] = hist[b * 16 + tid] / (float)(nn * nn);
    }
    __syncthreads();
    if (tid < 16) {
        float h = fc1b[tid];
        for (int f = 0; f < 32; ++f) h += feat[f] * fc1W[f * 16 + tid];
        red[tid] = fmaxf(h, 0.f);
    }
    __syncthreads();
    if (tid == 0) {
        float o = scb[0];
        for (int j = 0; j < 16; ++j) o += red[j] * scW[j];
        out[b] = 1.f / (1.f + expf(-o));
    }
}

// ---------------- launch ----------------
extern "C" void kernel_launch(void* const* d_in, const int* in_sizes, int n_in,
                              void* d_out, int out_size, void* d_ws, size_t ws_size,
                              hipStream_t stream) {
    const float* x1   = (const float*)d_in[0];
    const float* x2   = (const float*)d_in[1];
    const int*   ei1  = (const int*)d_in[2];
    const int*   ei2  = (const int*)d_in[3];
    const int*   bat1 = (const int*)d_in[4];
    const int*   bat2 = (const int*)d_in[5];
    const float* W1   = (const float*)d_in[6];
    const float* b1   = (const float*)d_in[7];
    const float* W2   = (const float*)d_in[8];
    const float* b2   = (const float*)d_in[9];
    const float* W3   = (const float*)d_in[10];
    const float* b3   = (const float*)d_in[11];
    const float* attW = (const float*)d_in[12];
    const float* ntnW = (const float*)d_in[13];
    const float* ntnV = (const float*)d_in[14];
    const float* ntnb = (const float*)d_in[15];
    const float* fc1W = (const float*)d_in[16];
    const float* fc1b = (const float*)d_in[17];
    const float* scW  = (const float*)d_in[18];
    const float* scb  = (const float*)d_in[19];
    float* out = (float*)d_out;

    // workspace layout (~55 MB)
    uint32* Hbuf  = (uint32*)d_ws;                       // hs rows: 131072*32 u32 (16.8 MB)
    uint32* Gb    = Hbuf + (size_t)TOT2 * 32;            // activations: 131072*32 u32 (16.8 MB)
    uint32* AFb   = Gb + (size_t)TOT2 * 32;              // AF: 131072*16 u32 (8.4 MB)
    uint32* bkt   = AFb + (size_t)TOT2 * 16;             // bucketed edges: 2M u32 (8.4 MB)
    float* dis    = (float*)(bkt + 2 * (size_t)Ec);      // 131072
    int*   gcnt   = (int*)(dis + TOT2);                  // 1024
    int*   goff   = gcnt + NB;                           // 1025
    int*   blkbase= goff + NB + 1;                       // 256*1024 (1 MB)
    int*   cnt    = blkbase + 256 * NB;                  // 256
    int*   st     = cnt + 256;                           // 256
    float* pool   = (float*)(st + 256);                  // 8192
    float* hist   = pool + 8192;                         // 2048
    float* bmn    = hist + 2048;                         // 1024
    float* bmx    = bmn + 1024;                          // 1024

    hipMemsetAsync(gcnt, 0, NB * sizeof(int), stream);
    hipMemsetAsync(hist, 0, 2048 * sizeof(float), stream);
    bs_k<<<1, 256, 0, stream>>>(bat1, bat2, cnt, st);
    bktcnt_k<<<256, 256, 0, stream>>>(ei1, ei2, gcnt, blkbase);
    scan1024_k<<<1, 1024, 0, stream>>>(gcnt, goff);
    bktfill_k<<<256, 256, 0, stream>>>(ei1, ei2, goff, blkbase, bkt);
    degdis_k<<<NB, 256, 0, stream>>>(goff, bkt, dis);

    // Layer 1 (K=128 f32 -> hs bf16)
    gemm_k<128, 64, false, false><<<512, 256, 0, stream>>>(x1, x2, W1, dis, Hbuf);
    agg_k<64><<<NB, 256, 0, stream>>>(Gb, Hbuf, dis, b1, goff, bkt);

    // Layer 2 (64 -> 64), relu fused into bf16 GEMM load
    gemm_k<64, 64, true, true><<<512, 256, 0, stream>>>(Gb, Gb, W2, dis, Hbuf);
    agg_k<64><<<NB, 256, 0, stream>>>(Gb, Hbuf, dis, b2, goff, bkt);

    // Layer 3 (64 -> 32)
    gemm_k<64, 32, true, true><<<512, 256, 0, stream>>>(Gb, Gb, W3, dis, Hbuf);
    agg_k<32><<<NB, 256, 0, stream>>>(AFb, Hbuf, dis, b3, goff, bkt);

    // Pooling, histogram, head
    attpool_k<<<256, 256, 0, stream>>>((const ushort16*)AFb, cnt, st, attW, pool);
    mm2_k<<<1024, 256, 0, stream>>>((const ushort16*)AFb, cnt, st, bmn, bmx);
    bin2_k<<<1024, 256, 0, stream>>>((const ushort16*)AFb, cnt, st, bmn, bmx, hist);
    final_k<<<128, 64, 0, stream>>>(pool, hist, cnt, ntnW, ntnV, ntnb, fc1W, fc1b, scW, scb, out);
}

// Round 9
// 470.900 us; speedup vs baseline: 4.2097x; 4.2097x over previous
//
#include <hip/hip_runtime.h>
#include <hip/hip_bf16.h>

// Problem constants (fixed by setup_inputs)
constexpr int    TOT = 65536;        // nodes per side
constexpr int    TOT2 = 131072;      // both sides
constexpr long long Ec = 16LL * TOT; // 1048576 edges per side
constexpr int    NB  = 1024;         // dst buckets (128 nodes each)
constexpr int    BKN = 128;          // nodes per bucket

typedef unsigned int   uint32;
typedef unsigned short ushort16;
typedef __attribute__((ext_vector_type(8))) short bf16x8;
typedef __attribute__((ext_vector_type(4))) float f32x4;

__device__ __forceinline__ float sigm(float x) { return 1.f / (1.f + __expf(-x)); }

__device__ __forceinline__ uint32 f2bf_rne(float x) {
    uint32 u = __float_as_uint(x);
    return (u + 0x7fffu + ((u >> 16) & 1u)) >> 16;
}
__device__ __forceinline__ float2 bf2f(uint32 u) {
    return make_float2(__uint_as_float(u << 16), __uint_as_float(u & 0xffff0000u));
}
__device__ __forceinline__ float bf1f(ushort16 u) {
    return __uint_as_float(((uint32)u) << 16);
}

// ---------------- batch segments via binary search (sorted batch arrays) ----------------
__global__ void bs_k(const int* __restrict__ b1, const int* __restrict__ b2,
                     int* __restrict__ cnt, int* __restrict__ st) {
    int t = threadIdx.x;
    const int* bat = (t < 128) ? b1 : b2;
    const int g = t & 127;
    int lo = 0, hi = TOT;
    while (lo < hi) { int m = (lo + hi) >> 1; if (bat[m] < g) lo = m + 1; else hi = m; }
    const int s0 = lo;
    hi = TOT;
    while (lo < hi) { int m = (lo + hi) >> 1; if (bat[m] < g + 1) lo = m + 1; else hi = m; }
    st[t] = s0;
    cnt[t] = lo - s0;
}

// ---------------- edge bucketing: pass A (count + reserve) ----------------
__global__ __launch_bounds__(256) void bktcnt_k(const int* __restrict__ ei1, const int* __restrict__ ei2,
                                                int* __restrict__ gcnt, int* __restrict__ blkbase) {
    __shared__ int hist[NB];
    const int tid = threadIdx.x, blk = blockIdx.x;
#pragma unroll
    for (int q = 0; q < 4; ++q) hist[q * 256 + tid] = 0;
    __syncthreads();
    const long long base = (long long)blk * 8192;
    for (int q = 0; q < 32; ++q) {
        long long e = base + q * 256 + tid;
        int d = (e < Ec) ? ei1[Ec + e] : (TOT + ei2[Ec + (e - Ec)]);
        atomicAdd(&hist[d >> 7], 1);
    }
    __syncthreads();
#pragma unroll
    for (int q = 0; q < 4; ++q) {
        int bb = q * 256 + tid;
        int c = hist[bb];
        int old = atomicAdd(&gcnt[bb], c);
        blkbase[blk * NB + bb] = old;
    }
}

// ---------------- exclusive scan of 1024 bucket counts ----------------
__global__ __launch_bounds__(1024) void scan1024_k(const int* __restrict__ gcnt, int* __restrict__ goff) {
    __shared__ int ws[16];
    const int t = threadIdx.x, lane = t & 63, wid = t >> 6;
    int v = gcnt[t];
    int inc = v;
#pragma unroll
    for (int d = 1; d < 64; d <<= 1) { int n = __shfl_up(inc, d, 64); if (lane >= d) inc += n; }
    if (lane == 63) ws[wid] = inc;
    __syncthreads();
    if (t == 0) { int o = 0; for (int q = 0; q < 16; ++q) { int x = ws[q]; ws[q] = o; o += x; } }
    __syncthreads();
    goff[t] = ws[wid] + inc - v;
    if (t == 1023) goff[NB] = ws[15] + inc;
}

// ---------------- edge bucketing: pass B (scatter into per-block runs) ----------------
// payload: src_global (17b) | dst_local (7b) << 20
__global__ __launch_bounds__(256) void bktfill_k(const int* __restrict__ ei1, const int* __restrict__ ei2,
                                                 const int* __restrict__ goff, const int* __restrict__ blkbase,
                                                 uint32* __restrict__ bkt) {
    __shared__ int hist[NB];
    __shared__ int hbase[NB];
    const int tid = threadIdx.x, blk = blockIdx.x;
#pragma unroll
    for (int q = 0; q < 4; ++q) {
        int bb = q * 256 + tid;
        hist[bb] = 0;
        hbase[bb] = goff[bb] + blkbase[blk * NB + bb];
    }
    __syncthreads();
    const long long base = (long long)blk * 8192;
    for (int q = 0; q < 32; ++q) {
        long long e = base + q * 256 + tid;
        int s, d;
        if (e < Ec) { s = ei1[e]; d = ei1[Ec + e]; }
        else        { long long e2 = e - Ec; s = TOT + ei2[e2]; d = TOT + ei2[Ec + e2]; }
        int bb = d >> 7;
        int lofs = atomicAdd(&hist[bb], 1);
        bkt[hbase[bb] + lofs] = (uint32)s | ((uint32)(d & 127) << 20);
    }
}

// ---------------- per-bucket counting sort -> CSR (src only) + rowptr + dis ----------------
// Two contiguous passes over the bucket's edges; no staging, no size cap.
__global__ __launch_bounds__(256) void bktsort_k(const int* __restrict__ goff, const uint32* __restrict__ bkt,
                                                 uint32* __restrict__ csr, int* __restrict__ rowptr,
                                                 float* __restrict__ dis) {
    __shared__ int deg[BKN], offs[BKN], cur[BKN];
    const int b = blockIdx.x, tid = threadIdx.x;
    const int e0 = goff[b], e1 = goff[b + 1];
    const int ne = e1 - e0;
    if (tid < BKN) deg[tid] = 0;
    __syncthreads();
    for (int i = tid; i < ne; i += 256) atomicAdd(&deg[bkt[e0 + i] >> 20], 1);
    __syncthreads();
    if (tid == 0) {
        int o = 0;
        for (int q = 0; q < BKN; ++q) { offs[q] = o; cur[q] = o; o += deg[q]; }
    }
    __syncthreads();
    for (int i = tid; i < ne; i += 256) {
        uint32 v = bkt[e0 + i];
        int dl = v >> 20;
        int pos = atomicAdd(&cur[dl], 1);
        csr[e0 + pos] = v & 0x1FFFF;
    }
    if (tid < BKN) {
        rowptr[b * BKN + tid] = e0 + offs[tid];
        dis[b * BKN + tid] = rsqrtf((float)deg[tid] + 1.0f);
    }
    if (b == 0 && tid == 0) rowptr[TOT2] = (int)(2 * Ec);
}

// ---------------- GEMM: out_bf16[M,NC] = dis[row] * ((relu?)X[M,K] @ W[K,NC]) ----------------
template<int K, int NC, bool RELU, bool XBF>
__global__ __launch_bounds__(256) void gemm_k(const void* __restrict__ X1v,
                                              const void* __restrict__ X2v,
                                              const float* __restrict__ W,
                                              const float* __restrict__ dis,
                                              uint32* __restrict__ out) {
    __shared__ float Ws[K * NC];
    const int tid = threadIdx.x;
    constexpr int WE4 = K * NC / 1024;
    {
        const float4* Wg = (const float4*)W;
        float4* Wp = (float4*)Ws;
#pragma unroll
        for (int it = 0; it < WE4; ++it) Wp[tid + it * 256] = Wg[tid + it * 256];
    }
    __syncthreads();
    const size_t row = (size_t)blockIdx.x * 256 + tid;
    float acc[NC];
#pragma unroll
    for (int j = 0; j < NC; ++j) acc[j] = 0.f;

    if (XBF) {
        const uint32* Xb = (row < TOT) ? (const uint32*)X1v + row * (K / 2)
                                       : (const uint32*)X2v + (row - TOT) * (K / 2);
        const uint4* Xr = (const uint4*)Xb;
#pragma unroll 2
        for (int k8 = 0; k8 < K / 8; ++k8) {
            uint4 xv = Xr[k8];
            float2 p0 = bf2f(xv.x), p1 = bf2f(xv.y), p2 = bf2f(xv.z), p3 = bf2f(xv.w);
            float xs[8] = {p0.x, p0.y, p1.x, p1.y, p2.x, p2.y, p3.x, p3.y};
            if (RELU) {
#pragma unroll
                for (int q = 0; q < 8; ++q) xs[q] = fmaxf(xs[q], 0.f);
            }
#pragma unroll
            for (int kk = 0; kk < 8; ++kk) {
#pragma unroll
                for (int j4 = 0; j4 < NC / 4; ++j4) {
                    float4 wv = *(const float4*)&Ws[(k8 * 8 + kk) * NC + j4 * 4];
                    acc[j4 * 4 + 0] += xs[kk] * wv.x;
                    acc[j4 * 4 + 1] += xs[kk] * wv.y;
                    acc[j4 * 4 + 2] += xs[kk] * wv.z;
                    acc[j4 * 4 + 3] += xs[kk] * wv.w;
                }
            }
        }
    } else {
        const float4* Xr = (row < TOT) ? (const float4*)((const float*)X1v + row * K)
                                       : (const float4*)((const float*)X2v + (row - TOT) * K);
#pragma unroll 2
        for (int k4 = 0; k4 < K / 4; ++k4) {
            float4 xv = Xr[k4];
            if (RELU) {
                xv.x = fmaxf(xv.x, 0.f); xv.y = fmaxf(xv.y, 0.f);
                xv.z = fmaxf(xv.z, 0.f); xv.w = fmaxf(xv.w, 0.f);
            }
            const float xs[4] = {xv.x, xv.y, xv.z, xv.w};
#pragma unroll
            for (int kk = 0; kk < 4; ++kk) {
#pragma unroll
                for (int j4 = 0; j4 < NC / 4; ++j4) {
                    float4 wv = *(const float4*)&Ws[(k4 * 4 + kk) * NC + j4 * 4];
                    acc[j4 * 4 + 0] += xs[kk] * wv.x;
                    acc[j4 * 4 + 1] += xs[kk] * wv.y;
                    acc[j4 * 4 + 2] += xs[kk] * wv.z;
                    acc[j4 * 4 + 3] += xs[kk] * wv.w;
                }
            }
        }
    }
    const float disv = dis[row];
    uint4* O4 = (uint4*)(out + row * (NC / 2));
#pragma unroll
    for (int j8 = 0; j8 < NC / 8; ++j8) {
        uint4 v;
        v.x = f2bf_rne(acc[j8 * 8 + 0] * disv) | (f2bf_rne(acc[j8 * 8 + 1] * disv) << 16);
        v.y = f2bf_rne(acc[j8 * 8 + 2] * disv) | (f2bf_rne(acc[j8 * 8 + 3] * disv) << 16);
        v.z = f2bf_rne(acc[j8 * 8 + 4] * disv) | (f2bf_rne(acc[j8 * 8 + 5] * disv) << 16);
        v.w = f2bf_rne(acc[j8 * 8 + 6] * disv) | (f2bf_rne(acc[j8 * 8 + 7] * disv) << 16);
        O4[j8] = v;
    }
}

// ---------------- GCN aggregation: unweighted CSR sum of hs rows ----------------
// out_bf16[i] = dis[i] * (hs[i] + sum_e hs[csr[e]]) + bias
template<int NC>
__global__ __launch_bounds__(256) void gatherb_k(uint32* __restrict__ out, const uint32* __restrict__ hs,
                                                 const float* __restrict__ dis, const float* __restrict__ bias,
                                                 const int* __restrict__ rowptr, const uint32* __restrict__ csr) {
    constexpr int TPN = NC / 2;
    constexpr int NPB = 256 / TPN;
    const int tid = threadIdx.x;
    const int cp = tid & (TPN - 1);
    const int node = blockIdx.x * NPB + tid / TPN;
    const float2 bb = ((const float2*)bias)[cp];
    float2 sv = bf2f(hs[(size_t)node * TPN + cp]);
    float acc0 = sv.x, acc1 = sv.y;
    int e = rowptr[node];
    const int e1 = rowptr[node + 1];
    for (; e + 1 < e1; e += 2) {
        int s0 = csr[e], s1 = csr[e + 1];
        float2 f0 = bf2f(hs[(size_t)s0 * TPN + cp]);
        float2 f1 = bf2f(hs[(size_t)s1 * TPN + cp]);
        acc0 += f0.x + f1.x;
        acc1 += f0.y + f1.y;
    }
    if (e < e1) {
        float2 f0 = bf2f(hs[(size_t)csr[e] * TPN + cp]);
        acc0 += f0.x; acc1 += f0.y;
    }
    const float dv = dis[node];
    out[(size_t)node * TPN + cp] = f2bf_rne(acc0 * dv + bb.x) | (f2bf_rne(acc1 * dv + bb.y) << 16);
}

// ---------------- attention pooling (bf16 AF input) ----------------
__global__ __launch_bounds__(256) void attpool_k(const ushort16* __restrict__ af,
                                                 const int* __restrict__ cnt, const int* __restrict__ st,
                                                 const float* __restrict__ attW, float* __restrict__ pool) {
    const int side = blockIdx.x >> 7, b = blockIdx.x & 127;
    const ushort16* h = af + (size_t)side * TOT * 32;
    const int c = cnt[side * 128 + b], s0 = st[side * 128 + b];
    const int f = threadIdx.x & 31, grp = threadIdx.x >> 5;
    __shared__ float red[8][32];
    __shared__ float mhS[32], tS[32];
    float acc = 0.f;
    for (int i = grp; i < c; i += 8) acc += bf1f(h[(size_t)(s0 + i) * 32 + f]);
    red[grp][f] = acc;
    __syncthreads();
    if (threadIdx.x < 32) { float tt = 0; for (int g = 0; g < 8; ++g) tt += red[g][f]; mhS[f] = tt / (float)c; }
    __syncthreads();
    if (threadIdx.x < 32) {
        float g = 0;
        for (int k = 0; k < 32; ++k) g += mhS[k] * attW[k * 32 + f];
        tS[f] = tanhf(g);
    }
    __syncthreads();
    const float tf = tS[f];
    acc = 0.f;
    for (int i = grp; i < c; i += 8) {
        float hv = bf1f(h[(size_t)(s0 + i) * 32 + f]);
        float pr = hv * tf;
#pragma unroll
        for (int m = 16; m; m >>= 1) pr += __shfl_xor(pr, m, 32);
        float sA = 1.f / (1.f + expf(-pr));
        acc += hv * sA;
    }
    __syncthreads();
    red[grp][f] = acc;
    __syncthreads();
    if (threadIdx.x < 32) {
        float tt = 0; for (int g = 0; g < 8; ++g) tt += red[g][f];
        pool[(size_t)(side * 128 + b) * 32 + f] = tt;
    }
}

// ---------------- histogram pass 1: MFMA min/max of raw dots ----------------
__global__ __launch_bounds__(256) void mm2_k(const ushort16* __restrict__ afb,
                                             const int* __restrict__ cnt, const int* __restrict__ st,
                                             float* __restrict__ bmn, float* __restrict__ bmx) {
    const int b = blockIdx.x >> 3, it8 = blockIdx.x & 7;
    const int c1 = cnt[b], c2 = cnt[128 + b];
    const int s1 = st[b], s2 = st[128 + b];
    const int nn = max(c1, c2);
    const int tid = threadIdx.x, lane = tid & 63, wave = tid >> 6;
    const int itile = it8 * 4 + wave;
    const int i0 = itile * 16;
    float lmn = 1e30f, lmx = -1e30f;
    if (i0 < nn) {
        const int arow = i0 + (lane & 15);
        const int koff = (lane >> 4) * 8;
        bf16x8 a = {0, 0, 0, 0, 0, 0, 0, 0};
        if (arow < c1) a = *(const bf16x8*)(afb + (size_t)(s1 + arow) * 32 + koff);
        const int ibase = i0 + (lane >> 4) * 4;
        const int njt = (nn + 15) >> 4;
        for (int jt = 0; jt < njt; ++jt) {
            const int brow = jt * 16 + (lane & 15);
            bf16x8 bb = {0, 0, 0, 0, 0, 0, 0, 0};
            if (brow < c2) bb = *(const bf16x8*)(afb + (size_t)(s2 + brow) * 32 + koff);
            f32x4 cc = {0.f, 0.f, 0.f, 0.f};
            cc = __builtin_amdgcn_mfma_f32_16x16x32_bf16(a, bb, cc, 0, 0, 0);
            if (brow < nn) {
#pragma unroll
                for (int r = 0; r < 4; ++r) {
                    if (ibase + r < nn) { lmn = fminf(lmn, cc[r]); lmx = fmaxf(lmx, cc[r]); }
                }
            }
        }
    }
    __shared__ float redn[256], redx[256];
    redn[tid] = lmn; redx[tid] = lmx;
    __syncthreads();
    for (int sr = 128; sr; sr >>= 1) {
        if (tid < sr) {
            redn[tid] = fminf(redn[tid], redn[tid + sr]);
            redx[tid] = fmaxf(redx[tid], redx[tid + sr]);
        }
        __syncthreads();
    }
    if (tid == 0) { bmn[blockIdx.x] = redn[0]; bmx[blockIdx.x] = redx[0]; }
}

// ---------------- histogram pass 2: MFMA + bin ----------------
__global__ __launch_bounds__(256) void bin2_k(const ushort16* __restrict__ afb,
                                              const int* __restrict__ cnt, const int* __restrict__ st,
                                              const float* __restrict__ bmn, const float* __restrict__ bmx,
                                              float* __restrict__ hist) {
    const int b = blockIdx.x >> 3, it8 = blockIdx.x & 7;
    const int c1 = cnt[b], c2 = cnt[128 + b];
    const int s1 = st[b], s2 = st[128 + b];
    const int nn = max(c1, c2);
    const int tid = threadIdx.x, lane = tid & 63, wave = tid >> 6;
    const int itile = it8 * 4 + wave;
    const int i0 = itile * 16;
    float dmn = 1e30f, dmx = -1e30f;
#pragma unroll
    for (int q = 0; q < 8; ++q) {
        dmn = fminf(dmn, bmn[(b << 3) + q]);
        dmx = fmaxf(dmx, bmx[(b << 3) + q]);
    }
    const float vMn = sigm(dmn), vMx = sigm(dmx);
    const float vScale = 16.f / ((vMx > vMn) ? (vMx - vMn) : 1.f);
    __shared__ int hloc[16 * 256];
    __shared__ int part[64];
#pragma unroll
    for (int q = 0; q < 16; ++q) hloc[q * 256 + tid] = 0;
    __syncthreads();
    if (i0 < nn) {
        const int arow = i0 + (lane & 15);
        const int koff = (lane >> 4) * 8;
        bf16x8 a = {0, 0, 0, 0, 0, 0, 0, 0};
        if (arow < c1) a = *(const bf16x8*)(afb + (size_t)(s1 + arow) * 32 + koff);
        const int ibase = i0 + (lane >> 4) * 4;
        const int njt = (nn + 15) >> 4;
        for (int jt = 0; jt < njt; ++jt) {
            const int brow = jt * 16 + (lane & 15);
            bf16x8 bb = {0, 0, 0, 0, 0, 0, 0, 0};
            if (brow < c2) bb = *(const bf16x8*)(afb + (size_t)(s2 + brow) * 32 + koff);
            f32x4 cc = {0.f, 0.f, 0.f, 0.f};
            cc = __builtin_amdgcn_mfma_f32_16x16x32_bf16(a, bb, cc, 0, 0, 0);
            if (brow < nn) {
#pragma unroll
                for (int r = 0; r < 4; ++r) {
                    if (ibase + r < nn) {
                        float t = (sigm(cc[r]) - vMn) * vScale;
                        int bi = (int)floorf(t);
                        bi = bi < 0 ? 0 : (bi > 15 ? 15 : bi);
                        hloc[bi * 256 + tid] += 1;
                    }
                }
            }
        }
    }
    __syncthreads();
    if (tid < 64) {
        const int bin = tid & 15, q = tid >> 4;
        int s = 0;
        for (int t2 = q * 64; t2 < q * 64 + 64; ++t2) s += hloc[bin * 256 + t2];
        part[tid] = s;
    }
    __syncthreads();
    if (tid < 16) {
        int s = part[tid] + part[16 + tid] + part[32 + tid] + part[48 + tid];
        atomicAdd(&hist[b * 16 + tid], (float)s);
    }
}

// ---------------- NTN + final MLP (one block per graph) ----------------
__global__ __launch_bounds__(64) void final_k(const float* __restrict__ pool, const float* __restrict__ hist,
                                              const int* __restrict__ cnt,
                                              const float* __restrict__ ntnW, const float* __restrict__ ntnV,
                                              const float* __restrict__ ntnb, const float* __restrict__ fc1W,
                                              const float* __restrict__ fc1b, const float* __restrict__ scW,
                                              const float* __restrict__ scb, float* __restrict__ out) {
    const int b = blockIdx.x;
    const int tid = threadIdx.x;
    __shared__ float P1[32], P2[32], feat[32], red[64];
    if (tid < 32) { P1[tid] = pool[b * 32 + tid]; P2[tid] = pool[4096 + b * 32 + tid]; }
    __syncthreads();
    const int k = tid & 15, part = tid >> 4;
    float acc = 0.f;
    for (int i = part * 8; i < part * 8 + 8; ++i) {
        float p1i = P1[i];
        for (int j = 0; j < 32; ++j) acc += p1i * P2[j] * ntnW[(i * 32 + j) * 16 + k];
    }
    red[tid] = acc;
    __syncthreads();
    if (tid < 16) {
        float bl = red[tid] + red[16 + tid] + red[32 + tid] + red[48 + tid];
        float blk = ntnb[tid];
        for (int i = 0; i < 32; ++i) blk += P1[i] * ntnV[tid * 64 + i];
        for (int j = 0; j < 32; ++j) blk += P2[j] * ntnV[tid * 64 + 32 + j];
        feat[tid] = fmaxf(bl + blk, 0.f);
        const int nn = max(cnt[b], cnt[128 + b]);
        feat[16 + tid] = hist[b * 16 + tid] / (float)(nn * nn);
    }
    __syncthreads();
    if (tid < 16) {
        float h = fc1b[tid];
        for (int f = 0; f < 32; ++f) h += feat[f] * fc1W[f * 16 + tid];
        red[tid] = fmaxf(h, 0.f);
    }
    __syncthreads();
    if (tid == 0) {
        float o = scb[0];
        for (int j = 0; j < 16; ++j) o += red[j] * scW[j];
        out[b] = 1.f / (1.f + expf(-o));
    }
}

// ---------------- launch ----------------
extern "C" void kernel_launch(void* const* d_in, const int* in_sizes, int n_in,
                              void* d_out, int out_size, void* d_ws, size_t ws_size,
                              hipStream_t stream) {
    const float* x1   = (const float*)d_in[0];
    const float* x2   = (const float*)d_in[1];
    const int*   ei1  = (const int*)d_in[2];
    const int*   ei2  = (const int*)d_in[3];
    const int*   bat1 = (const int*)d_in[4];
    const int*   bat2 = (const int*)d_in[5];
    const float* W1   = (const float*)d_in[6];
    const float* b1   = (const float*)d_in[7];
    const float* W2   = (const float*)d_in[8];
    const float* b2   = (const float*)d_in[9];
    const float* W3   = (const float*)d_in[10];
    const float* b3   = (const float*)d_in[11];
    const float* attW = (const float*)d_in[12];
    const float* ntnW = (const float*)d_in[13];
    const float* ntnV = (const float*)d_in[14];
    const float* ntnb = (const float*)d_in[15];
    const float* fc1W = (const float*)d_in[16];
    const float* fc1b = (const float*)d_in[17];
    const float* scW  = (const float*)d_in[18];
    const float* scb  = (const float*)d_in[19];
    float* out = (float*)d_out;

    // workspace layout (~64 MB)
    uint32* Hbuf  = (uint32*)d_ws;                       // hs rows: 131072*32 u32 (16.8 MB)
    uint32* Gb    = Hbuf + (size_t)TOT2 * 32;            // activations: 131072*32 u32 (16.8 MB)
    uint32* AFb   = Gb + (size_t)TOT2 * 32;              // AF: 131072*16 u32 (8.4 MB)
    uint32* bkt   = AFb + (size_t)TOT2 * 16;             // bucket-grouped edges: 2M u32 (8.4 MB)
    uint32* csr   = bkt + 2 * (size_t)Ec;                // CSR-sorted src: 2M u32 (8.4 MB)
    float* dis    = (float*)(csr + 2 * (size_t)Ec);      // 131072
    int*   rowptr = (int*)(dis + TOT2);                  // 131073
    int*   gcnt   = rowptr + TOT2 + 1;                   // 1024
    int*   goff   = gcnt + NB;                           // 1025
    int*   blkbase= goff + NB + 1;                       // 256*1024 (1 MB)
    int*   cnt    = blkbase + 256 * NB;                  // 256
    int*   st     = cnt + 256;                           // 256
    float* pool   = (float*)(st + 256);                  // 8192
    float* hist   = pool + 8192;                         // 2048
    float* bmn    = hist + 2048;                         // 1024
    float* bmx    = bmn + 1024;                          // 1024

    hipMemsetAsync(gcnt, 0, NB * sizeof(int), stream);
    hipMemsetAsync(hist, 0, 2048 * sizeof(float), stream);
    bs_k<<<1, 256, 0, stream>>>(bat1, bat2, cnt, st);
    bktcnt_k<<<256, 256, 0, stream>>>(ei1, ei2, gcnt, blkbase);
    scan1024_k<<<1, 1024, 0, stream>>>(gcnt, goff);
    bktfill_k<<<256, 256, 0, stream>>>(ei1, ei2, goff, blkbase, bkt);
    bktsort_k<<<NB, 256, 0, stream>>>(goff, bkt, csr, rowptr, dis);

    // Layer 1 (K=128 f32 -> hs bf16)
    gemm_k<128, 64, false, false><<<512, 256, 0, stream>>>(x1, x2, W1, dis, Hbuf);
    gatherb_k<64><<<TOT2 / 8, 256, 0, stream>>>(Gb, Hbuf, dis, b1, rowptr, csr);

    // Layer 2 (64 -> 64), relu fused into bf16 GEMM load
    gemm_k<64, 64, true, true><<<512, 256, 0, stream>>>(Gb, Gb, W2, dis, Hbuf);
    gatherb_k<64><<<TOT2 / 8, 256, 0, stream>>>(Gb, Hbuf, dis, b2, rowptr, csr);

    // Layer 3 (64 -> 32)
    gemm_k<64, 32, true, true><<<512, 256, 0, stream>>>(Gb, Gb, W3, dis, Hbuf);
    gatherb_k<32><<<TOT2 / 16, 256, 0, stream>>>(AFb, Hbuf, dis, b3, rowptr, csr);

    // Pooling, histogram, head
    attpool_k<<<256, 256, 0, stream>>>((const ushort16*)AFb, cnt, st, attW, pool);
    mm2_k<<<1024, 256, 0, stream>>>((const ushort16*)AFb, cnt, st, bmn, bmx);
    bin2_k<<<1024, 256, 0, stream>>>((const ushort16*)AFb, cnt, st, bmn, bmx, hist);
    final_k<<<128, 64, 0, stream>>>(pool, hist, cnt, ntnW, ntnV, ntnb, fc1W, fc1b, scW, scb, out);
}

// Round 10
// 410.400 us; speedup vs baseline: 4.8303x; 1.1474x over previous
//
#include <hip/hip_runtime.h>
#include <hip/hip_bf16.h>

// Problem constants (fixed by setup_inputs)
constexpr int    TOT = 65536;        // nodes per side
constexpr int    TOT2 = 131072;      // both sides
constexpr long long Ec = 16LL * TOT; // 1048576 edges per side
constexpr int    NB  = 1024;         // dst buckets (128 nodes each)
constexpr int    BKN = 128;          // nodes per bucket

typedef unsigned int   uint32;
typedef unsigned short ushort16;
typedef __attribute__((ext_vector_type(8))) short bf16x8;
typedef __attribute__((ext_vector_type(4))) float f32x4;

__device__ __forceinline__ float sigm(float x) { return 1.f / (1.f + __expf(-x)); }

__device__ __forceinline__ uint32 f2bf_rne(float x) {
    uint32 u = __float_as_uint(x);
    return (u + 0x7fffu + ((u >> 16) & 1u)) >> 16;
}
__device__ __forceinline__ float2 bf2f(uint32 u) {
    return make_float2(__uint_as_float(u << 16), __uint_as_float(u & 0xffff0000u));
}
__device__ __forceinline__ float bf1f(ushort16 u) {
    return __uint_as_float(((uint32)u) << 16);
}

// ---------------- batch segments via binary search (sorted batch arrays) ----------------
__global__ void bs_k(const int* __restrict__ b1, const int* __restrict__ b2,
                     int* __restrict__ cnt, int* __restrict__ st) {
    int t = threadIdx.x;
    const int* bat = (t < 128) ? b1 : b2;
    const int g = t & 127;
    int lo = 0, hi = TOT;
    while (lo < hi) { int m = (lo + hi) >> 1; if (bat[m] < g) lo = m + 1; else hi = m; }
    const int s0 = lo;
    hi = TOT;
    while (lo < hi) { int m = (lo + hi) >> 1; if (bat[m] < g + 1) lo = m + 1; else hi = m; }
    st[t] = s0;
    cnt[t] = lo - s0;
}

// ---------------- edge bucketing: pass A (count + reserve) ----------------
__global__ __launch_bounds__(256) void bktcnt_k(const int* __restrict__ ei1, const int* __restrict__ ei2,
                                                int* __restrict__ gcnt, int* __restrict__ blkbase) {
    __shared__ int hist[NB];
    const int tid = threadIdx.x, blk = blockIdx.x;
#pragma unroll
    for (int q = 0; q < 4; ++q) hist[q * 256 + tid] = 0;
    __syncthreads();
    const long long base = (long long)blk * 8192;
    for (int q = 0; q < 32; ++q) {
        long long e = base + q * 256 + tid;
        int d = (e < Ec) ? ei1[Ec + e] : (TOT + ei2[Ec + (e - Ec)]);
        atomicAdd(&hist[d >> 7], 1);
    }
    __syncthreads();
#pragma unroll
    for (int q = 0; q < 4; ++q) {
        int bb = q * 256 + tid;
        int c = hist[bb];
        int old = atomicAdd(&gcnt[bb], c);
        blkbase[blk * NB + bb] = old;
    }
}

// ---------------- exclusive scan of 1024 bucket counts ----------------
__global__ __launch_bounds__(1024) void scan1024_k(const int* __restrict__ gcnt, int* __restrict__ goff) {
    __shared__ int ws[16];
    const int t = threadIdx.x, lane = t & 63, wid = t >> 6;
    int v = gcnt[t];
    int inc = v;
#pragma unroll
    for (int d = 1; d < 64; d <<= 1) { int n = __shfl_up(inc, d, 64); if (lane >= d) inc += n; }
    if (lane == 63) ws[wid] = inc;
    __syncthreads();
    if (t == 0) { int o = 0; for (int q = 0; q < 16; ++q) { int x = ws[q]; ws[q] = o; o += x; } }
    __syncthreads();
    goff[t] = ws[wid] + inc - v;
    if (t == 1023) goff[NB] = ws[15] + inc;
}

// ---------------- edge bucketing: pass B (scatter into per-block runs) ----------------
// payload: src_global (17b) | dst_local (7b) << 20
__global__ __launch_bounds__(256) void bktfill_k(const int* __restrict__ ei1, const int* __restrict__ ei2,
                                                 const int* __restrict__ goff, const int* __restrict__ blkbase,
                                                 uint32* __restrict__ bkt) {
    __shared__ int hist[NB];
    __shared__ int hbase[NB];
    const int tid = threadIdx.x, blk = blockIdx.x;
#pragma unroll
    for (int q = 0; q < 4; ++q) {
        int bb = q * 256 + tid;
        hist[bb] = 0;
        hbase[bb] = goff[bb] + blkbase[blk * NB + bb];
    }
    __syncthreads();
    const long long base = (long long)blk * 8192;
    for (int q = 0; q < 32; ++q) {
        long long e = base + q * 256 + tid;
        int s, d;
        if (e < Ec) { s = ei1[e]; d = ei1[Ec + e]; }
        else        { long long e2 = e - Ec; s = TOT + ei2[e2]; d = TOT + ei2[Ec + e2]; }
        int bb = d >> 7;
        int lofs = atomicAdd(&hist[bb], 1);
        bkt[hbase[bb] + lofs] = (uint32)s | ((uint32)(d & 127) << 20);
    }
}

// ---------------- per-bucket counting sort -> CSR (src only) + rowptr + dis ----------------
__global__ __launch_bounds__(256) void bktsort_k(const int* __restrict__ goff, const uint32* __restrict__ bkt,
                                                 uint32* __restrict__ csr, int* __restrict__ rowptr,
                                                 float* __restrict__ dis) {
    __shared__ int deg[BKN], offs[BKN], cur[BKN];
    const int b = blockIdx.x, tid = threadIdx.x;
    const int e0 = goff[b], e1 = goff[b + 1];
    const int ne = e1 - e0;
    if (tid < BKN) deg[tid] = 0;
    __syncthreads();
    for (int i = tid; i < ne; i += 256) atomicAdd(&deg[bkt[e0 + i] >> 20], 1);
    __syncthreads();
    if (tid == 0) {
        int o = 0;
        for (int q = 0; q < BKN; ++q) { offs[q] = o; cur[q] = o; o += deg[q]; }
    }
    __syncthreads();
    for (int i = tid; i < ne; i += 256) {
        uint32 v = bkt[e0 + i];
        int dl = v >> 20;
        int pos = atomicAdd(&cur[dl], 1);
        csr[e0 + pos] = v & 0x1FFFF;
    }
    if (tid < BKN) {
        rowptr[b * BKN + tid] = e0 + offs[tid];
        dis[b * BKN + tid] = rsqrtf((float)deg[tid] + 1.0f);
    }
    if (b == 0 && tid == 0) rowptr[TOT2] = (int)(2 * Ec);
}

// ---------------- GEMM: out_bf16[M,NC] = dis[row] * ((relu?)X[M,K] @ W[K,NC]) ----------------
template<int K, int NC, bool RELU, bool XBF>
__global__ __launch_bounds__(256) void gemm_k(const void* __restrict__ X1v,
                                              const void* __restrict__ X2v,
                                              const float* __restrict__ W,
                                              const float* __restrict__ dis,
                                              uint32* __restrict__ out) {
    __shared__ float Ws[K * NC];
    const int tid = threadIdx.x;
    constexpr int WE4 = K * NC / 1024;
    {
        const float4* Wg = (const float4*)W;
        float4* Wp = (float4*)Ws;
#pragma unroll
        for (int it = 0; it < WE4; ++it) Wp[tid + it * 256] = Wg[tid + it * 256];
    }
    __syncthreads();
    const size_t row = (size_t)blockIdx.x * 256 + tid;
    float acc[NC];
#pragma unroll
    for (int j = 0; j < NC; ++j) acc[j] = 0.f;

    if (XBF) {
        const uint32* Xb = (row < TOT) ? (const uint32*)X1v + row * (K / 2)
                                       : (const uint32*)X2v + (row - TOT) * (K / 2);
        const uint4* Xr = (const uint4*)Xb;
#pragma unroll 2
        for (int k8 = 0; k8 < K / 8; ++k8) {
            uint4 xv = Xr[k8];
            float2 p0 = bf2f(xv.x), p1 = bf2f(xv.y), p2 = bf2f(xv.z), p3 = bf2f(xv.w);
            float xs[8] = {p0.x, p0.y, p1.x, p1.y, p2.x, p2.y, p3.x, p3.y};
            if (RELU) {
#pragma unroll
                for (int q = 0; q < 8; ++q) xs[q] = fmaxf(xs[q], 0.f);
            }
#pragma unroll
            for (int kk = 0; kk < 8; ++kk) {
#pragma unroll
                for (int j4 = 0; j4 < NC / 4; ++j4) {
                    float4 wv = *(const float4*)&Ws[(k8 * 8 + kk) * NC + j4 * 4];
                    acc[j4 * 4 + 0] += xs[kk] * wv.x;
                    acc[j4 * 4 + 1] += xs[kk] * wv.y;
                    acc[j4 * 4 + 2] += xs[kk] * wv.z;
                    acc[j4 * 4 + 3] += xs[kk] * wv.w;
                }
            }
        }
    } else {
        const float4* Xr = (row < TOT) ? (const float4*)((const float*)X1v + row * K)
                                       : (const float4*)((const float*)X2v + (row - TOT) * K);
#pragma unroll 2
        for (int k4 = 0; k4 < K / 4; ++k4) {
            float4 xv = Xr[k4];
            if (RELU) {
                xv.x = fmaxf(xv.x, 0.f); xv.y = fmaxf(xv.y, 0.f);
                xv.z = fmaxf(xv.z, 0.f); xv.w = fmaxf(xv.w, 0.f);
            }
            const float xs[4] = {xv.x, xv.y, xv.z, xv.w};
#pragma unroll
            for (int kk = 0; kk < 4; ++kk) {
#pragma unroll
                for (int j4 = 0; j4 < NC / 4; ++j4) {
                    float4 wv = *(const float4*)&Ws[(k4 * 4 + kk) * NC + j4 * 4];
                    acc[j4 * 4 + 0] += xs[kk] * wv.x;
                    acc[j4 * 4 + 1] += xs[kk] * wv.y;
                    acc[j4 * 4 + 2] += xs[kk] * wv.z;
                    acc[j4 * 4 + 3] += xs[kk] * wv.w;
                }
            }
        }
    }
    const float disv = dis[row];
    uint4* O4 = (uint4*)(out + row * (NC / 2));
#pragma unroll
    for (int j8 = 0; j8 < NC / 8; ++j8) {
        uint4 v;
        v.x = f2bf_rne(acc[j8 * 8 + 0] * disv) | (f2bf_rne(acc[j8 * 8 + 1] * disv) << 16);
        v.y = f2bf_rne(acc[j8 * 8 + 2] * disv) | (f2bf_rne(acc[j8 * 8 + 3] * disv) << 16);
        v.z = f2bf_rne(acc[j8 * 8 + 4] * disv) | (f2bf_rne(acc[j8 * 8 + 5] * disv) << 16);
        v.w = f2bf_rne(acc[j8 * 8 + 6] * disv) | (f2bf_rne(acc[j8 * 8 + 7] * disv) << 16);
        O4[j8] = v;
    }
}

// ---------------- GCN aggregation: unweighted CSR sum of hs rows ----------------
// out_bf16[i] = dis[i] * (hs[i] + sum_e hs[csr[e]]) + bias
// 8-deep load pipeline + XCD side-swizzle (side0 -> xcd 0-3, side1 -> 4-7).
template<int NC>
__global__ __launch_bounds__(256) void gatherb_k(uint32* __restrict__ out, const uint32* __restrict__ hs,
                                                 const float* __restrict__ dis, const float* __restrict__ bias,
                                                 const int* __restrict__ rowptr, const uint32* __restrict__ csr) {
    constexpr int TPN = NC / 2;
    constexpr int NPB = 256 / TPN;
    // swizzle: assume round-robin blockIdx->XCD; bijective remap either way
    int bid;
    {
        const int xcd = blockIdx.x & 7, idx = blockIdx.x >> 3;
        const int half = gridDim.x >> 1;
        bid = (xcd < 4) ? (idx * 4 + xcd) : (half + idx * 4 + (xcd - 4));
    }
    const int tid = threadIdx.x;
    const int cp = tid & (TPN - 1);
    const int node = bid * NPB + tid / TPN;
    const float2 bb = ((const float2*)bias)[cp];
    float2 sv = bf2f(hs[(size_t)node * TPN + cp]);
    float acc0 = sv.x, acc1 = sv.y;
    int e = rowptr[node];
    const int e1 = rowptr[node + 1];
    // 8-deep pipelined chunks
    for (; e + 8 <= e1; e += 8) {
        uint32 p[8];
#pragma unroll
        for (int q = 0; q < 8; ++q) p[q] = hs[(size_t)csr[e + q] * TPN + cp];
#pragma unroll
        for (int q = 0; q < 8; ++q) { float2 f = bf2f(p[q]); acc0 += f.x; acc1 += f.y; }
    }
    if (e + 4 <= e1) {
        uint32 p[4];
#pragma unroll
        for (int q = 0; q < 4; ++q) p[q] = hs[(size_t)csr[e + q] * TPN + cp];
#pragma unroll
        for (int q = 0; q < 4; ++q) { float2 f = bf2f(p[q]); acc0 += f.x; acc1 += f.y; }
        e += 4;
    }
    for (; e < e1; ++e) {
        float2 f = bf2f(hs[(size_t)csr[e] * TPN + cp]);
        acc0 += f.x; acc1 += f.y;
    }
    const float dv = dis[node];
    out[(size_t)node * TPN + cp] = f2bf_rne(acc0 * dv + bb.x) | (f2bf_rne(acc1 * dv + bb.y) << 16);
}

// ---------------- attention pooling (bf16 AF input) ----------------
__global__ __launch_bounds__(256) void attpool_k(const ushort16* __restrict__ af,
                                                 const int* __restrict__ cnt, const int* __restrict__ st,
                                                 const float* __restrict__ attW, float* __restrict__ pool) {
    const int side = blockIdx.x >> 7, b = blockIdx.x & 127;
    const ushort16* h = af + (size_t)side * TOT * 32;
    const int c = cnt[side * 128 + b], s0 = st[side * 128 + b];
    const int f = threadIdx.x & 31, grp = threadIdx.x >> 5;
    __shared__ float red[8][32];
    __shared__ float mhS[32], tS[32];
    float acc = 0.f;
    for (int i = grp; i < c; i += 8) acc += bf1f(h[(size_t)(s0 + i) * 32 + f]);
    red[grp][f] = acc;
    __syncthreads();
    if (threadIdx.x < 32) { float tt = 0; for (int g = 0; g < 8; ++g) tt += red[g][f]; mhS[f] = tt / (float)c; }
    __syncthreads();
    if (threadIdx.x < 32) {
        float g = 0;
        for (int k = 0; k < 32; ++k) g += mhS[k] * attW[k * 32 + f];
        tS[f] = tanhf(g);
    }
    __syncthreads();
    const float tf = tS[f];
    acc = 0.f;
    for (int i = grp; i < c; i += 8) {
        float hv = bf1f(h[(size_t)(s0 + i) * 32 + f]);
        float pr = hv * tf;
#pragma unroll
        for (int m = 16; m; m >>= 1) pr += __shfl_xor(pr, m, 32);
        float sA = 1.f / (1.f + expf(-pr));
        acc += hv * sA;
    }
    __syncthreads();
    red[grp][f] = acc;
    __syncthreads();
    if (threadIdx.x < 32) {
        float tt = 0; for (int g = 0; g < 8; ++g) tt += red[g][f];
        pool[(size_t)(side * 128 + b) * 32 + f] = tt;
    }
}

// ---------------- histogram pass 1: MFMA min/max of raw dots ----------------
__global__ __launch_bounds__(256) void mm2_k(const ushort16* __restrict__ afb,
                                             const int* __restrict__ cnt, const int* __restrict__ st,
                                             float* __restrict__ bmn, float* __restrict__ bmx) {
    const int b = blockIdx.x >> 3, it8 = blockIdx.x & 7;
    const int c1 = cnt[b], c2 = cnt[128 + b];
    const int s1 = st[b], s2 = st[128 + b];
    const int nn = max(c1, c2);
    const int tid = threadIdx.x, lane = tid & 63, wave = tid >> 6;
    const int itile = it8 * 4 + wave;
    const int i0 = itile * 16;
    float lmn = 1e30f, lmx = -1e30f;
    if (i0 < nn) {
        const int arow = i0 + (lane & 15);
        const int koff = (lane >> 4) * 8;
        bf16x8 a = {0, 0, 0, 0, 0, 0, 0, 0};
        if (arow < c1) a = *(const bf16x8*)(afb + (size_t)(s1 + arow) * 32 + koff);
        const int ibase = i0 + (lane >> 4) * 4;
        const int njt = (nn + 15) >> 4;
        for (int jt = 0; jt < njt; ++jt) {
            const int brow = jt * 16 + (lane & 15);
            bf16x8 bb = {0, 0, 0, 0, 0, 0, 0, 0};
            if (brow < c2) bb = *(const bf16x8*)(afb + (size_t)(s2 + brow) * 32 + koff);
            f32x4 cc = {0.f, 0.f, 0.f, 0.f};
            cc = __builtin_amdgcn_mfma_f32_16x16x32_bf16(a, bb, cc, 0, 0, 0);
            if (brow < nn) {
#pragma unroll
                for (int r = 0; r < 4; ++r) {
                    if (ibase + r < nn) { lmn = fminf(lmn, cc[r]); lmx = fmaxf(lmx, cc[r]); }
                }
            }
        }
    }
    __shared__ float redn[256], redx[256];
    redn[tid] = lmn; redx[tid] = lmx;
    __syncthreads();
    for (int sr = 128; sr; sr >>= 1) {
        if (tid < sr) {
            redn[tid] = fminf(redn[tid], redn[tid + sr]);
            redx[tid] = fmaxf(redx[tid], redx[tid + sr]);
        }
        __syncthreads();
    }
    if (tid == 0) { bmn[blockIdx.x] = redn[0]; bmx[blockIdx.x] = redx[0]; }
}

// ---------------- histogram pass 2: MFMA + bin ----------------
__global__ __launch_bounds__(256) void bin2_k(const ushort16* __restrict__ afb,
                                              const int* __restrict__ cnt, const int* __restrict__ st,
                                              const float* __restrict__ bmn, const float* __restrict__ bmx,
                                              float* __restrict__ hist) {
    const int b = blockIdx.x >> 3, it8 = blockIdx.x & 7;
    const int c1 = cnt[b], c2 = cnt[128 + b];
    const int s1 = st[b], s2 = st[128 + b];
    const int nn = max(c1, c2);
    const int tid = threadIdx.x, lane = tid & 63, wave = tid >> 6;
    const int itile = it8 * 4 + wave;
    const int i0 = itile * 16;
    float dmn = 1e30f, dmx = -1e30f;
#pragma unroll
    for (int q = 0; q < 8; ++q) {
        dmn = fminf(dmn, bmn[(b << 3) + q]);
        dmx = fmaxf(dmx, bmx[(b << 3) + q]);
    }
    const float vMn = sigm(dmn), vMx = sigm(dmx);
    const float vScale = 16.f / ((vMx > vMn) ? (vMx - vMn) : 1.f);
    __shared__ int hloc[16 * 256];
    __shared__ int part[64];
#pragma unroll
    for (int q = 0; q < 16; ++q) hloc[q * 256 + tid] = 0;
    __syncthreads();
    if (i0 < nn) {
        const int arow = i0 + (lane & 15);
        const int koff = (lane >> 4) * 8;
        bf16x8 a = {0, 0, 0, 0, 0, 0, 0, 0};
        if (arow < c1) a = *(const bf16x8*)(afb + (size_t)(s1 + arow) * 32 + koff);
        const int ibase = i0 + (lane >> 4) * 4;
        const int njt = (nn + 15) >> 4;
        for (int jt = 0; jt < njt; ++jt) {
            const int brow = jt * 16 + (lane & 15);
            bf16x8 bb = {0, 0, 0, 0, 0, 0, 0, 0};
            if (brow < c2) bb = *(const bf16x8*)(afb + (size_t)(s2 + brow) * 32 + koff);
            f32x4 cc = {0.f, 0.f, 0.f, 0.f};
            cc = __builtin_amdgcn_mfma_f32_16x16x32_bf16(a, bb, cc, 0, 0, 0);
            if (brow < nn) {
#pragma unroll
                for (int r = 0; r < 4; ++r) {
                    if (ibase + r < nn) {
                        float t = (sigm(cc[r]) - vMn) * vScale;
                        int bi = (int)floorf(t);
                        bi = bi < 0 ? 0 : (bi > 15 ? 15 : bi);
                        hloc[bi * 256 + tid] += 1;
                    }
                }
            }
        }
    }
    __syncthreads();
    if (tid < 64) {
        const int bin = tid & 15, q = tid >> 4;
        int s = 0;
        for (int t2 = q * 64; t2 < q * 64 + 64; ++t2) s += hloc[bin * 256 + t2];
        part[tid] = s;
    }
    __syncthreads();
    if (tid < 16) {
        int s = part[tid] + part[16 + tid] + part[32 + tid] + part[48 + tid];
        atomicAdd(&hist[b * 16 + tid], (float)s);
    }
}

// ---------------- NTN + final MLP (one block per graph) ----------------
__global__ __launch_bounds__(64) void final_k(const float* __restrict__ pool, const float* __restrict__ hist,
                                              const int* __restrict__ cnt,
                                              const float* __restrict__ ntnW, const float* __restrict__ ntnV,
                                              const float* __restrict__ ntnb, const float* __restrict__ fc1W,
                                              const float* __restrict__ fc1b, const float* __restrict__ scW,
                                              const float* __restrict__ scb, float* __restrict__ out) {
    const int b = blockIdx.x;
    const int tid = threadIdx.x;
    __shared__ float P1[32], P2[32], feat[32], red[64];
    if (tid < 32) { P1[tid] = pool[b * 32 + tid]; P2[tid] = pool[4096 + b * 32 + tid]; }
    __syncthreads();
    const int k = tid & 15, part = tid >> 4;
    float acc = 0.f;
    for (int i = part * 8; i < part * 8 + 8; ++i) {
        float p1i = P1[i];
        for (int j = 0; j < 32; ++j) acc += p1i * P2[j] * ntnW[(i * 32 + j) * 16 + k];
    }
    red[tid] = acc;
    __syncthreads();
    if (tid < 16) {
        float bl = red[tid] + red[16 + tid] + red[32 + tid] + red[48 + tid];
        float blk = ntnb[tid];
        for (int i = 0; i < 32; ++i) blk += P1[i] * ntnV[tid * 64 + i];
        for (int j = 0; j < 32; ++j) blk += P2[j] * ntnV[tid * 64 + 32 + j];
        feat[tid] = fmaxf(bl + blk, 0.f);
        const int nn = max(cnt[b], cnt[128 + b]);
        feat[16 + tid] = hist[b * 16 + tid] / (float)(nn * nn);
    }
    __syncthreads();
    if (tid < 16) {
        float h = fc1b[tid];
        for (int f = 0; f < 32; ++f) h += feat[f] * fc1W[f * 16 + tid];
        red[tid] = fmaxf(h, 0.f);
    }
    __syncthreads();
    if (tid == 0) {
        float o = scb[0];
        for (int j = 0; j < 16; ++j) o += red[j] * scW[j];
        out[b] = 1.f / (1.f + expf(-o));
    }
}

// ---------------- launch ----------------
extern "C" void kernel_launch(void* const* d_in, const int* in_sizes, int n_in,
                              void* d_out, int out_size, void* d_ws, size_t ws_size,
                              hipStream_t stream) {
    const float* x1   = (const float*)d_in[0];
    const float* x2   = (const float*)d_in[1];
    const int*   ei1  = (const int*)d_in[2];
    const int*   ei2  = (const int*)d_in[3];
    const int*   bat1 = (const int*)d_in[4];
    const int*   bat2 = (const int*)d_in[5];
    const float* W1   = (const float*)d_in[6];
    const float* b1   = (const float*)d_in[7];
    const float* W2   = (const float*)d_in[8];
    const float* b2   = (const float*)d_in[9];
    const float* W3   = (const float*)d_in[10];
    const float* b3   = (const float*)d_in[11];
    const float* attW = (const float*)d_in[12];
    const float* ntnW = (const float*)d_in[13];
    const float* ntnV = (const float*)d_in[14];
    const float* ntnb = (const float*)d_in[15];
    const float* fc1W = (const float*)d_in[16];
    const float* fc1b = (const float*)d_in[17];
    const float* scW  = (const float*)d_in[18];
    const float* scb  = (const float*)d_in[19];
    float* out = (float*)d_out;

    // workspace layout (~64 MB)
    uint32* Hbuf  = (uint32*)d_ws;                       // hs rows: 131072*32 u32 (16.8 MB)
    uint32* Gb    = Hbuf + (size_t)TOT2 * 32;            // activations: 131072*32 u32 (16.8 MB)
    uint32* AFb   = Gb + (size_t)TOT2 * 32;              // AF: 131072*16 u32 (8.4 MB)
    uint32* bkt   = AFb + (size_t)TOT2 * 16;             // bucket-grouped edges: 2M u32 (8.4 MB)
    uint32* csr   = bkt + 2 * (size_t)Ec;                // CSR-sorted src: 2M u32 (8.4 MB)
    float* dis    = (float*)(csr + 2 * (size_t)Ec);      // 131072
    int*   rowptr = (int*)(dis + TOT2);                  // 131073
    int*   gcnt   = rowptr + TOT2 + 1;                   // 1024
    int*   goff   = gcnt + NB;                           // 1025
    int*   blkbase= goff + NB + 1;                       // 256*1024 (1 MB)
    int*   cnt    = blkbase + 256 * NB;                  // 256
    int*   st     = cnt + 256;                           // 256
    float* pool   = (float*)(st + 256);                  // 8192
    float* hist   = pool + 8192;                         // 2048
    float* bmn    = hist + 2048;                         // 1024
    float* bmx    = bmn + 1024;                          // 1024

    hipMemsetAsync(gcnt, 0, NB * sizeof(int), stream);
    hipMemsetAsync(hist, 0, 2048 * sizeof(float), stream);
    bs_k<<<1, 256, 0, stream>>>(bat1, bat2, cnt, st);
    bktcnt_k<<<256, 256, 0, stream>>>(ei1, ei2, gcnt, blkbase);
    scan1024_k<<<1, 1024, 0, stream>>>(gcnt, goff);
    bktfill_k<<<256, 256, 0, stream>>>(ei1, ei2, goff, blkbase, bkt);
    bktsort_k<<<NB, 256, 0, stream>>>(goff, bkt, csr, rowptr, dis);

    // Layer 1 (K=128 f32 -> hs bf16)
    gemm_k<128, 64, false, false><<<512, 256, 0, stream>>>(x1, x2, W1, dis, Hbuf);
    gatherb_k<64><<<TOT2 / 8, 256, 0, stream>>>(Gb, Hbuf, dis, b1, rowptr, csr);

    // Layer 2 (64 -> 64), relu fused into bf16 GEMM load
    gemm_k<64, 64, true, true><<<512, 256, 0, stream>>>(Gb, Gb, W2, dis, Hbuf);
    gatherb_k<64><<<TOT2 / 8, 256, 0, stream>>>(Gb, Hbuf, dis, b2, rowptr, csr);

    // Layer 3 (64 -> 32)
    gemm_k<64, 32, true, true><<<512, 256, 0, stream>>>(Gb, Gb, W3, dis, Hbuf);
    gatherb_k<32><<<TOT2 / 16, 256, 0, stream>>>(AFb, Hbuf, dis, b3, rowptr, csr);

    // Pooling, histogram, head
    attpool_k<<<256, 256, 0, stream>>>((const ushort16*)AFb, cnt, st, attW, pool);
    mm2_k<<<1024, 256, 0, stream>>>((const ushort16*)AFb, cnt, st, bmn, bmx);
    bin2_k<<<1024, 256, 0, stream>>>((const ushort16*)AFb, cnt, st, bmn, bmx, hist);
    final_k<<<128, 64, 0, stream>>>(pool, hist, cnt, ntnW, ntnV, ntnb, fc1W, fc1b, scW, scb, out);
}

// Round 11
// 359.422 us; speedup vs baseline: 5.5154x; 1.1418x over previous
//
#include <hip/hip_runtime.h>
#include <hip/hip_bf16.h>

// Problem constants (fixed by setup_inputs)
constexpr int    TOT = 65536;        // nodes per side
constexpr int    TOT2 = 131072;      // both sides
constexpr long long Ec = 16LL * TOT; // 1048576 edges per side
constexpr int    NB  = 1024;         // dst buckets (128 nodes each)
constexpr int    BKN = 128;          // nodes per bucket

typedef unsigned int   uint32;
typedef unsigned short ushort16;
typedef __attribute__((ext_vector_type(8))) short bf16x8;
typedef __attribute__((ext_vector_type(4))) float f32x4;

__device__ __forceinline__ float sigm(float x) { return 1.f / (1.f + __expf(-x)); }

__device__ __forceinline__ uint32 f2bf_rne(float x) {
    uint32 u = __float_as_uint(x);
    return (u + 0x7fffu + ((u >> 16) & 1u)) >> 16;
}
__device__ __forceinline__ float2 bf2f(uint32 u) {
    return make_float2(__uint_as_float(u << 16), __uint_as_float(u & 0xffff0000u));
}
__device__ __forceinline__ float bf1f(ushort16 u) {
    return __uint_as_float(((uint32)u) << 16);
}
// relu on a packed bf16x2 word: zero each half whose sign bit is set
__device__ __forceinline__ uint32 relu_bf2(uint32 v) {
    uint32 keep = (((int)v < 0) ? 0u : 0xFFFF0000u) | ((v & 0x8000u) ? 0u : 0x0000FFFFu);
    return v & keep;
}

// ---------------- batch segments via binary search (sorted batch arrays) ----------------
__global__ void bs_k(const int* __restrict__ b1, const int* __restrict__ b2,
                     int* __restrict__ cnt, int* __restrict__ st) {
    int t = threadIdx.x;
    const int* bat = (t < 128) ? b1 : b2;
    const int g = t & 127;
    int lo = 0, hi = TOT;
    while (lo < hi) { int m = (lo + hi) >> 1; if (bat[m] < g) lo = m + 1; else hi = m; }
    const int s0 = lo;
    hi = TOT;
    while (lo < hi) { int m = (lo + hi) >> 1; if (bat[m] < g + 1) lo = m + 1; else hi = m; }
    st[t] = s0;
    cnt[t] = lo - s0;
}

// ---------------- edge bucketing: pass A (count + reserve) ----------------
__global__ __launch_bounds__(256) void bktcnt_k(const int* __restrict__ ei1, const int* __restrict__ ei2,
                                                int* __restrict__ gcnt, int* __restrict__ blkbase) {
    __shared__ int hist[NB];
    const int tid = threadIdx.x, blk = blockIdx.x;
#pragma unroll
    for (int q = 0; q < 4; ++q) hist[q * 256 + tid] = 0;
    __syncthreads();
    const long long base = (long long)blk * 8192;
    for (int q = 0; q < 32; ++q) {
        long long e = base + q * 256 + tid;
        int d = (e < Ec) ? ei1[Ec + e] : (TOT + ei2[Ec + (e - Ec)]);
        atomicAdd(&hist[d >> 7], 1);
    }
    __syncthreads();
#pragma unroll
    for (int q = 0; q < 4; ++q) {
        int bb = q * 256 + tid;
        int c = hist[bb];
        int old = atomicAdd(&gcnt[bb], c);
        blkbase[blk * NB + bb] = old;
    }
}

// ---------------- exclusive scan of 1024 bucket counts ----------------
__global__ __launch_bounds__(1024) void scan1024_k(const int* __restrict__ gcnt, int* __restrict__ goff) {
    __shared__ int ws[16];
    const int t = threadIdx.x, lane = t & 63, wid = t >> 6;
    int v = gcnt[t];
    int inc = v;
#pragma unroll
    for (int d = 1; d < 64; d <<= 1) { int n = __shfl_up(inc, d, 64); if (lane >= d) inc += n; }
    if (lane == 63) ws[wid] = inc;
    __syncthreads();
    if (t == 0) { int o = 0; for (int q = 0; q < 16; ++q) { int x = ws[q]; ws[q] = o; o += x; } }
    __syncthreads();
    goff[t] = ws[wid] + inc - v;
    if (t == 1023) goff[NB] = ws[15] + inc;
}

// ---------------- edge bucketing: pass B (scatter into per-block runs) ----------------
// payload: src_global (17b) | dst_local (7b) << 20
__global__ __launch_bounds__(256) void bktfill_k(const int* __restrict__ ei1, const int* __restrict__ ei2,
                                                 const int* __restrict__ goff, const int* __restrict__ blkbase,
                                                 uint32* __restrict__ bkt) {
    __shared__ int hist[NB];
    __shared__ int hbase[NB];
    const int tid = threadIdx.x, blk = blockIdx.x;
#pragma unroll
    for (int q = 0; q < 4; ++q) {
        int bb = q * 256 + tid;
        hist[bb] = 0;
        hbase[bb] = goff[bb] + blkbase[blk * NB + bb];
    }
    __syncthreads();
    const long long base = (long long)blk * 8192;
    for (int q = 0; q < 32; ++q) {
        long long e = base + q * 256 + tid;
        int s, d;
        if (e < Ec) { s = ei1[e]; d = ei1[Ec + e]; }
        else        { long long e2 = e - Ec; s = TOT + ei2[e2]; d = TOT + ei2[Ec + e2]; }
        int bb = d >> 7;
        int lofs = atomicAdd(&hist[bb], 1);
        bkt[hbase[bb] + lofs] = (uint32)s | ((uint32)(d & 127) << 20);
    }
}

// ---------------- per-bucket counting sort -> CSR (src only) + rowptr + dis ----------------
__global__ __launch_bounds__(256) void bktsort_k(const int* __restrict__ goff, const uint32* __restrict__ bkt,
                                                 uint32* __restrict__ csr, int* __restrict__ rowptr,
                                                 float* __restrict__ dis) {
    __shared__ int deg[BKN], offs[BKN], cur[BKN];
    const int b = blockIdx.x, tid = threadIdx.x;
    const int e0 = goff[b], e1 = goff[b + 1];
    const int ne = e1 - e0;
    if (tid < BKN) deg[tid] = 0;
    __syncthreads();
    for (int i = tid; i < ne; i += 256) atomicAdd(&deg[bkt[e0 + i] >> 20], 1);
    __syncthreads();
    if (tid == 0) {
        int o = 0;
        for (int q = 0; q < BKN; ++q) { offs[q] = o; cur[q] = o; o += deg[q]; }
    }
    __syncthreads();
    for (int i = tid; i < ne; i += 256) {
        uint32 v = bkt[e0 + i];
        int dl = v >> 20;
        int pos = atomicAdd(&cur[dl], 1);
        csr[e0 + pos] = v & 0x1FFFF;
    }
    if (tid < BKN) {
        rowptr[b * BKN + tid] = e0 + offs[tid];
        dis[b * BKN + tid] = rsqrtf((float)deg[tid] + 1.0f);
    }
    if (b == 0 && tid == 0) rowptr[TOT2] = (int)(2 * Ec);
}

// ---------------- weight transpose + bf16 convert: Wt[j][k] = bf16(W[k][j]) ----------------
__global__ void wtcvt_k(const float* __restrict__ W1, const float* __restrict__ W2,
                        const float* __restrict__ W3, ushort16* __restrict__ Wt1,
                        ushort16* __restrict__ Wt2, ushort16* __restrict__ Wt3) {
    int t = blockIdx.x * 256 + threadIdx.x;       // 8192 + 4096 + 2048 = 14336
    if (t < 8192) {                               // W1: 128x64 -> Wt1: 64x128
        int j = t >> 7, k = t & 127;
        Wt1[t] = (ushort16)f2bf_rne(W1[k * 64 + j]);
    } else if (t < 12288) {                       // W2: 64x64 -> Wt2: 64x64
        int u = t - 8192; int j = u >> 6, k = u & 63;
        Wt2[u] = (ushort16)f2bf_rne(W2[k * 64 + j]);
    } else if (t < 14336) {                       // W3: 64x32 -> Wt3: 32x64
        int u = t - 12288; int j = u >> 6, k = u & 63;
        Wt3[u] = (ushort16)f2bf_rne(W3[k * 32 + j]);
    }
}

// ---------------- MFMA GEMM: out_bf16[M,NC] = dis[row] * ((relu?)X[M,K] @ W[K,NC]) ----------------
// One wave = 16 rows x NC cols. Fragment pattern identical to mm2_k/bin2_k (verified).
// XBF: X rows packed bf16 (relu via sign-mask); else f32 rows converted in-register.
template<int K, int NC, bool RELU, bool XBF>
__global__ __launch_bounds__(256) void gemmf_k(const void* __restrict__ X1v,
                                               const void* __restrict__ X2v,
                                               const ushort16* __restrict__ Wt,   // [NC][K] bf16
                                               const float* __restrict__ dis,
                                               ushort16* __restrict__ out) {
    constexpr int NK = K / 32;                     // K-slices per MFMA chain
    const int tid = threadIdx.x, lane = tid & 63, wave = tid >> 6;
    const int i0 = (blockIdx.x * 4 + wave) * 16;
    const int arow = i0 + (lane & 15);
    const int ks0 = (lane >> 4) * 8;               // bf16-element offset within 32-chunk
    // A fragments
    bf16x8 a[NK];
    if (XBF) {
        const uint32* Xr = (arow < TOT) ? (const uint32*)X1v + (size_t)arow * (K / 2)
                                        : (const uint32*)X2v + (size_t)(arow - TOT) * (K / 2);
#pragma unroll
        for (int s = 0; s < NK; ++s) {
            uint4 v = *(const uint4*)(Xr + s * 16 + ks0 / 2);
            if (RELU) { v.x = relu_bf2(v.x); v.y = relu_bf2(v.y); v.z = relu_bf2(v.z); v.w = relu_bf2(v.w); }
            a[s] = *(bf16x8*)&v;
        }
    } else {
        const float* Xr = (arow < TOT) ? (const float*)X1v + (size_t)arow * K
                                       : (const float*)X2v + (size_t)(arow - TOT) * K;
#pragma unroll
        for (int s = 0; s < NK; ++s) {
            float4 v0 = *(const float4*)(Xr + s * 32 + ks0);
            float4 v1 = *(const float4*)(Xr + s * 32 + ks0 + 4);
            if (RELU) {
                v0.x = fmaxf(v0.x, 0.f); v0.y = fmaxf(v0.y, 0.f); v0.z = fmaxf(v0.z, 0.f); v0.w = fmaxf(v0.w, 0.f);
                v1.x = fmaxf(v1.x, 0.f); v1.y = fmaxf(v1.y, 0.f); v1.z = fmaxf(v1.z, 0.f); v1.w = fmaxf(v1.w, 0.f);
            }
            uint4 p;
            p.x = f2bf_rne(v0.x) | (f2bf_rne(v0.y) << 16);
            p.y = f2bf_rne(v0.z) | (f2bf_rne(v0.w) << 16);
            p.z = f2bf_rne(v1.x) | (f2bf_rne(v1.y) << 16);
            p.w = f2bf_rne(v1.z) | (f2bf_rne(v1.w) << 16);
            a[s] = *(bf16x8*)&p;
        }
    }
    // dis for this lane's 4 output rows
    float dv[4];
#pragma unroll
    for (int r = 0; r < 4; ++r) dv[r] = dis[i0 + (lane >> 4) * 4 + r];
#pragma unroll
    for (int jt = 0; jt < NC / 16; ++jt) {
        const int col = jt * 16 + (lane & 15);
        f32x4 cc = {0.f, 0.f, 0.f, 0.f};
#pragma unroll
        for (int s = 0; s < NK; ++s) {
            bf16x8 b = *(const bf16x8*)(Wt + (size_t)col * K + s * 32 + ks0);
            cc = __builtin_amdgcn_mfma_f32_16x16x32_bf16(a[s], b, cc, 0, 0, 0);
        }
#pragma unroll
        for (int r = 0; r < 4; ++r) {
            const int row = i0 + (lane >> 4) * 4 + r;
            out[(size_t)row * NC + col] = (ushort16)f2bf_rne(cc[r] * dv[r]);
        }
    }
}

// ---------------- GCN aggregation: unweighted CSR sum of hs rows ----------------
// out_bf16[i] = dis[i] * (hs[i] + sum_e hs[csr[e]]) + bias
// 8-deep load pipeline + XCD side-swizzle.
template<int NC>
__global__ __launch_bounds__(256) void gatherb_k(uint32* __restrict__ out, const uint32* __restrict__ hs,
                                                 const float* __restrict__ dis, const float* __restrict__ bias,
                                                 const int* __restrict__ rowptr, const uint32* __restrict__ csr) {
    constexpr int TPN = NC / 2;
    constexpr int NPB = 256 / TPN;
    int bid;
    {
        const int xcd = blockIdx.x & 7, idx = blockIdx.x >> 3;
        const int half = gridDim.x >> 1;
        bid = (xcd < 4) ? (idx * 4 + xcd) : (half + idx * 4 + (xcd - 4));
    }
    const int tid = threadIdx.x;
    const int cp = tid & (TPN - 1);
    const int node = bid * NPB + tid / TPN;
    const float2 bb = ((const float2*)bias)[cp];
    float2 sv = bf2f(hs[(size_t)node * TPN + cp]);
    float acc0 = sv.x, acc1 = sv.y;
    int e = rowptr[node];
    const int e1 = rowptr[node + 1];
    for (; e + 8 <= e1; e += 8) {
        uint32 p[8];
#pragma unroll
        for (int q = 0; q < 8; ++q) p[q] = hs[(size_t)csr[e + q] * TPN + cp];
#pragma unroll
        for (int q = 0; q < 8; ++q) { float2 f = bf2f(p[q]); acc0 += f.x; acc1 += f.y; }
    }
    if (e + 4 <= e1) {
        uint32 p[4];
#pragma unroll
        for (int q = 0; q < 4; ++q) p[q] = hs[(size_t)csr[e + q] * TPN + cp];
#pragma unroll
        for (int q = 0; q < 4; ++q) { float2 f = bf2f(p[q]); acc0 += f.x; acc1 += f.y; }
        e += 4;
    }
    for (; e < e1; ++e) {
        float2 f = bf2f(hs[(size_t)csr[e] * TPN + cp]);
        acc0 += f.x; acc1 += f.y;
    }
    const float dv = dis[node];
    out[(size_t)node * TPN + cp] = f2bf_rne(acc0 * dv + bb.x) | (f2bf_rne(acc1 * dv + bb.y) << 16);
}

// ---------------- attention pooling (bf16 AF input) ----------------
__global__ __launch_bounds__(256) void attpool_k(const ushort16* __restrict__ af,
                                                 const int* __restrict__ cnt, const int* __restrict__ st,
                                                 const float* __restrict__ attW, float* __restrict__ pool) {
    const int side = blockIdx.x >> 7, b = blockIdx.x & 127;
    const ushort16* h = af + (size_t)side * TOT * 32;
    const int c = cnt[side * 128 + b], s0 = st[side * 128 + b];
    const int f = threadIdx.x & 31, grp = threadIdx.x >> 5;
    __shared__ float red[8][32];
    __shared__ float mhS[32], tS[32];
    float acc = 0.f;
    for (int i = grp; i < c; i += 8) acc += bf1f(h[(size_t)(s0 + i) * 32 + f]);
    red[grp][f] = acc;
    __syncthreads();
    if (threadIdx.x < 32) { float tt = 0; for (int g = 0; g < 8; ++g) tt += red[g][f]; mhS[f] = tt / (float)c; }
    __syncthreads();
    if (threadIdx.x < 32) {
        float g = 0;
        for (int k = 0; k < 32; ++k) g += mhS[k] * attW[k * 32 + f];
        tS[f] = tanhf(g);
    }
    __syncthreads();
    const float tf = tS[f];
    acc = 0.f;
    for (int i = grp; i < c; i += 8) {
        float hv = bf1f(h[(size_t)(s0 + i) * 32 + f]);
        float pr = hv * tf;
#pragma unroll
        for (int m = 16; m; m >>= 1) pr += __shfl_xor(pr, m, 32);
        float sA = 1.f / (1.f + expf(-pr));
        acc += hv * sA;
    }
    __syncthreads();
    red[grp][f] = acc;
    __syncthreads();
    if (threadIdx.x < 32) {
        float tt = 0; for (int g = 0; g < 8; ++g) tt += red[g][f];
        pool[(size_t)(side * 128 + b) * 32 + f] = tt;
    }
}

// ---------------- histogram pass 1: MFMA min/max of raw dots ----------------
__global__ __launch_bounds__(256) void mm2_k(const ushort16* __restrict__ afb,
                                             const int* __restrict__ cnt, const int* __restrict__ st,
                                             float* __restrict__ bmn, float* __restrict__ bmx) {
    const int b = blockIdx.x >> 3, it8 = blockIdx.x & 7;
    const int c1 = cnt[b], c2 = cnt[128 + b];
    const int s1 = st[b], s2 = st[128 + b];
    const int nn = max(c1, c2);
    const int tid = threadIdx.x, lane = tid & 63, wave = tid >> 6;
    const int itile = it8 * 4 + wave;
    const int i0 = itile * 16;
    float lmn = 1e30f, lmx = -1e30f;
    if (i0 < nn) {
        const int arow = i0 + (lane & 15);
        const int koff = (lane >> 4) * 8;
        bf16x8 a = {0, 0, 0, 0, 0, 0, 0, 0};
        if (arow < c1) a = *(const bf16x8*)(afb + (size_t)(s1 + arow) * 32 + koff);
        const int ibase = i0 + (lane >> 4) * 4;
        const int njt = (nn + 15) >> 4;
        for (int jt = 0; jt < njt; ++jt) {
            const int brow = jt * 16 + (lane & 15);
            bf16x8 bb = {0, 0, 0, 0, 0, 0, 0, 0};
            if (brow < c2) bb = *(const bf16x8*)(afb + (size_t)(s2 + brow) * 32 + koff);
            f32x4 cc = {0.f, 0.f, 0.f, 0.f};
            cc = __builtin_amdgcn_mfma_f32_16x16x32_bf16(a, bb, cc, 0, 0, 0);
            if (brow < nn) {
#pragma unroll
                for (int r = 0; r < 4; ++r) {
                    if (ibase + r < nn) { lmn = fminf(lmn, cc[r]); lmx = fmaxf(lmx, cc[r]); }
                }
            }
        }
    }
    __shared__ float redn[256], redx[256];
    redn[tid] = lmn; redx[tid] = lmx;
    __syncthreads();
    for (int sr = 128; sr; sr >>= 1) {
        if (tid < sr) {
            redn[tid] = fminf(redn[tid], redn[tid + sr]);
            redx[tid] = fmaxf(redx[tid], redx[tid + sr]);
        }
        __syncthreads();
    }
    if (tid == 0) { bmn[blockIdx.x] = redn[0]; bmx[blockIdx.x] = redx[0]; }
}

// ---------------- histogram pass 2: MFMA + bin ----------------
__global__ __launch_bounds__(256) void bin2_k(const ushort16* __restrict__ afb,
                                              const int* __restrict__ cnt, const int* __restrict__ st,
                                              const float* __restrict__ bmn, const float* __restrict__ bmx,
                                              float* __restrict__ hist) {
    const int b = blockIdx.x >> 3, it8 = blockIdx.x & 7;
    const int c1 = cnt[b], c2 = cnt[128 + b];
    const int s1 = st[b], s2 = st[128 + b];
    const int nn = max(c1, c2);
    const int tid = threadIdx.x, lane = tid & 63, wave = tid >> 6;
    const int itile = it8 * 4 + wave;
    const int i0 = itile * 16;
    float dmn = 1e30f, dmx = -1e30f;
#pragma unroll
    for (int q = 0; q < 8; ++q) {
        dmn = fminf(dmn, bmn[(b << 3) + q]);
        dmx = fmaxf(dmx, bmx[(b << 3) + q]);
    }
    const float vMn = sigm(dmn), vMx = sigm(dmx);
    const float vScale = 16.f / ((vMx > vMn) ? (vMx - vMn) : 1.f);
    __shared__ int hloc[16 * 256];
    __shared__ int part[64];
#pragma unroll
    for (int q = 0; q < 16; ++q) hloc[q * 256 + tid] = 0;
    __syncthreads();
    if (i0 < nn) {
        const int arow = i0 + (lane & 15);
        const int koff = (lane >> 4) * 8;
        bf16x8 a = {0, 0, 0, 0, 0, 0, 0, 0};
        if (arow < c1) a = *(const bf16x8*)(afb + (size_t)(s1 + arow) * 32 + koff);
        const int ibase = i0 + (lane >> 4) * 4;
        const int njt = (nn + 15) >> 4;
        for (int jt = 0; jt < njt; ++jt) {
            const int brow = jt * 16 + (lane & 15);
            bf16x8 bb = {0, 0, 0, 0, 0, 0, 0, 0};
            if (brow < c2) bb = *(const bf16x8*)(afb + (size_t)(s2 + brow) * 32 + koff);
            f32x4 cc = {0.f, 0.f, 0.f, 0.f};
            cc = __builtin_amdgcn_mfma_f32_16x16x32_bf16(a, bb, cc, 0, 0, 0);
            if (brow < nn) {
#pragma unroll
                for (int r = 0; r < 4; ++r) {
                    if (ibase + r < nn) {
                        float t = (sigm(cc[r]) - vMn) * vScale;
                        int bi = (int)floorf(t);
                        bi = bi < 0 ? 0 : (bi > 15 ? 15 : bi);
                        hloc[bi * 256 + tid] += 1;
                    }
                }
            }
        }
    }
    __syncthreads();
    if (tid < 64) {
        const int bin = tid & 15, q = tid >> 4;
        int s = 0;
        for (int t2 = q * 64; t2 < q * 64 + 64; ++t2) s += hloc[bin * 256 + t2];
        part[tid] = s;
    }
    __syncthreads();
    if (tid < 16) {
        int s = part[tid] + part[16 + tid] + part[32 + tid] + part[48 + tid];
        atomicAdd(&hist[b * 16 + tid], (float)s);
    }
}

// ---------------- NTN + final MLP (one block per graph) ----------------
__global__ __launch_bounds__(64) void final_k(const float* __restrict__ pool, const float* __restrict__ hist,
                                              const int* __restrict__ cnt,
                                              const float* __restrict__ ntnW, const float* __restrict__ ntnV,
                                              const float* __restrict__ ntnb, const float* __restrict__ fc1W,
                                              const float* __restrict__ fc1b, const float* __restrict__ scW,
                                              const float* __restrict__ scb, float* __restrict__ out) {
    const int b = blockIdx.x;
    const int tid = threadIdx.x;
    __shared__ float P1[32], P2[32], feat[32], red[64];
    if (tid < 32) { P1[tid] = pool[b * 32 + tid]; P2[tid] = pool[4096 + b * 32 + tid]; }
    __syncthreads();
    const int k = tid & 15, part = tid >> 4;
    float acc = 0.f;
    for (int i = part * 8; i < part * 8 + 8; ++i) {
        float p1i = P1[i];
        for (int j = 0; j < 32; ++j) acc += p1i * P2[j] * ntnW[(i * 32 + j) * 16 + k];
    }
    red[tid] = acc;
    __syncthreads();
    if (tid < 16) {
        float bl = red[tid] + red[16 + tid] + red[32 + tid] + red[48 + tid];
        float blk = ntnb[tid];
        for (int i = 0; i < 32; ++i) blk += P1[i] * ntnV[tid * 64 + i];
        for (int j = 0; j < 32; ++j) blk += P2[j] * ntnV[tid * 64 + 32 + j];
        feat[tid] = fmaxf(bl + blk, 0.f);
        const int nn = max(cnt[b], cnt[128 + b]);
        feat[16 + tid] = hist[b * 16 + tid] / (float)(nn * nn);
    }
    __syncthreads();
    if (tid < 16) {
        float h = fc1b[tid];
        for (int f = 0; f < 32; ++f) h += feat[f] * fc1W[f * 16 + tid];
        red[tid] = fmaxf(h, 0.f);
    }
    __syncthreads();
    if (tid == 0) {
        float o = scb[0];
        for (int j = 0; j < 16; ++j) o += red[j] * scW[j];
        out[b] = 1.f / (1.f + expf(-o));
    }
}

// ---------------- launch ----------------
extern "C" void kernel_launch(void* const* d_in, const int* in_sizes, int n_in,
                              void* d_out, int out_size, void* d_ws, size_t ws_size,
                              hipStream_t stream) {
    const float* x1   = (const float*)d_in[0];
    const float* x2   = (const float*)d_in[1];
    const int*   ei1  = (const int*)d_in[2];
    const int*   ei2  = (const int*)d_in[3];
    const int*   bat1 = (const int*)d_in[4];
    const int*   bat2 = (const int*)d_in[5];
    const float* W1   = (const float*)d_in[6];
    const float* b1   = (const float*)d_in[7];
    const float* W2   = (const float*)d_in[8];
    const float* b2   = (const float*)d_in[9];
    const float* W3   = (const float*)d_in[10];
    const float* b3   = (const float*)d_in[11];
    const float* attW = (const float*)d_in[12];
    const float* ntnW = (const float*)d_in[13];
    const float* ntnV = (const float*)d_in[14];
    const float* ntnb = (const float*)d_in[15];
    const float* fc1W = (const float*)d_in[16];
    const float* fc1b = (const float*)d_in[17];
    const float* scW  = (const float*)d_in[18];
    const float* scb  = (const float*)d_in[19];
    float* out = (float*)d_out;

    // workspace layout (~64 MB)
    uint32* Hbuf  = (uint32*)d_ws;                       // hs rows: 131072*32 u32 (16.8 MB)
    uint32* Gb    = Hbuf + (size_t)TOT2 * 32;            // activations: 131072*32 u32 (16.8 MB)
    uint32* AFb   = Gb + (size_t)TOT2 * 32;              // AF: 131072*16 u32 (8.4 MB)
    uint32* bkt   = AFb + (size_t)TOT2 * 16;             // bucket-grouped edges: 2M u32 (8.4 MB)
    uint32* csr   = bkt + 2 * (size_t)Ec;                // CSR-sorted src: 2M u32 (8.4 MB)
    float* dis    = (float*)(csr + 2 * (size_t)Ec);      // 131072
    int*   rowptr = (int*)(dis + TOT2);                  // 131073
    int*   gcnt   = rowptr + TOT2 + 1;                   // 1024
    int*   goff   = gcnt + NB;                           // 1025
    int*   blkbase= goff + NB + 1;                       // 256*1024 (1 MB)
    int*   cnt    = blkbase + 256 * NB;                  // 256
    int*   st     = cnt + 256;                           // 256
    float* pool   = (float*)(st + 256);                  // 8192
    float* hist   = pool + 8192;                         // 2048
    float* bmn    = hist + 2048;                         // 1024
    float* bmx    = bmn + 1024;                          // 1024
    ushort16* Wt1 = (ushort16*)(bmx + 1024);             // 64*128 bf16
    ushort16* Wt2 = Wt1 + 8192;                          // 64*64
    ushort16* Wt3 = Wt2 + 4096;                          // 32*64

    hipMemsetAsync(gcnt, 0, NB * sizeof(int), stream);
    hipMemsetAsync(hist, 0, 2048 * sizeof(float), stream);
    bs_k<<<1, 256, 0, stream>>>(bat1, bat2, cnt, st);
    wtcvt_k<<<56, 256, 0, stream>>>(W1, W2, W3, Wt1, Wt2, Wt3);
    bktcnt_k<<<256, 256, 0, stream>>>(ei1, ei2, gcnt, blkbase);
    scan1024_k<<<1, 1024, 0, stream>>>(gcnt, goff);
    bktfill_k<<<256, 256, 0, stream>>>(ei1, ei2, goff, blkbase, bkt);
    bktsort_k<<<NB, 256, 0, stream>>>(goff, bkt, csr, rowptr, dis);

    // Layer 1 (K=128 f32 -> hs bf16), MFMA
    gemmf_k<128, 64, false, false><<<2048, 256, 0, stream>>>(x1, x2, Wt1, dis, (ushort16*)Hbuf);
    gatherb_k<64><<<TOT2 / 8, 256, 0, stream>>>(Gb, Hbuf, dis, b1, rowptr, csr);

    // Layer 2 (64 -> 64), relu fused into A-fragment load
    gemmf_k<64, 64, true, true><<<2048, 256, 0, stream>>>(Gb, Gb, Wt2, dis, (ushort16*)Hbuf);
    gatherb_k<64><<<TOT2 / 8, 256, 0, stream>>>(Gb, Hbuf, dis, b2, rowptr, csr);

    // Layer 3 (64 -> 32)
    gemmf_k<64, 32, true, true><<<2048, 256, 0, stream>>>(Gb, Gb, Wt3, dis, (ushort16*)Hbuf);
    gatherb_k<32><<<TOT2 / 16, 256, 0, stream>>>(AFb, Hbuf, dis, b3, rowptr, csr);

    // Pooling, histogram, head
    attpool_k<<<256, 256, 0, stream>>>((const ushort16*)AFb, cnt, st, attW, pool);
    mm2_k<<<1024, 256, 0, stream>>>((const ushort16*)AFb, cnt, st, bmn, bmx);
    bin2_k<<<1024, 256, 0, stream>>>((const ushort16*)AFb, cnt, st, bmn, bmx, hist);
    final_k<<<128, 64, 0, stream>>>(pool, hist, cnt, ntnW, ntnV, ntnb, fc1W, fc1b, scW, scb, out);
}

// Round 12
// 356.622 us; speedup vs baseline: 5.5587x; 1.0079x over previous
//
#include <hip/hip_runtime.h>
#include <hip/hip_bf16.h>

// Problem constants (fixed by setup_inputs)
constexpr int    TOT = 65536;        // nodes per side
constexpr int    TOT2 = 131072;      // both sides
constexpr long long Ec = 16LL * TOT; // 1048576 edges per side
constexpr int    NB  = 1024;         // dst buckets (128 nodes each)
constexpr int    BKN = 128;          // nodes per bucket
constexpr int    NKEY = 1024;        // counting-sort keys: 128 dl x 8 src-octants

typedef unsigned int   uint32;
typedef unsigned short ushort16;
typedef __attribute__((ext_vector_type(8))) short bf16x8;
typedef __attribute__((ext_vector_type(4))) float f32x4;

__device__ __forceinline__ float sigm(float x) { return 1.f / (1.f + __expf(-x)); }

__device__ __forceinline__ uint32 f2bf_rne(float x) {
    uint32 u = __float_as_uint(x);
    return (u + 0x7fffu + ((u >> 16) & 1u)) >> 16;
}
__device__ __forceinline__ float2 bf2f(uint32 u) {
    return make_float2(__uint_as_float(u << 16), __uint_as_float(u & 0xffff0000u));
}
__device__ __forceinline__ float bf1f(ushort16 u) {
    return __uint_as_float(((uint32)u) << 16);
}
__device__ __forceinline__ uint32 relu_bf2(uint32 v) {
    uint32 keep = (((int)v < 0) ? 0u : 0xFFFF0000u) | ((v & 0x8000u) ? 0u : 0x0000FFFFu);
    return v & keep;
}

// ---------------- setup: weight transpose/convert + batch segments ----------------
__global__ void setup_k(const float* __restrict__ W1, const float* __restrict__ W2,
                        const float* __restrict__ W3, ushort16* __restrict__ Wt1,
                        ushort16* __restrict__ Wt2, ushort16* __restrict__ Wt3,
                        const int* __restrict__ b1, const int* __restrict__ b2,
                        int* __restrict__ cnt, int* __restrict__ st) {
    int t = blockIdx.x * 256 + threadIdx.x;
    if (t < 8192) {                               // W1: 128x64 -> Wt1: 64x128
        int j = t >> 7, k = t & 127;
        Wt1[t] = (ushort16)f2bf_rne(W1[k * 64 + j]);
    } else if (t < 12288) {                       // W2: 64x64 -> Wt2: 64x64
        int u = t - 8192; int j = u >> 6, k = u & 63;
        Wt2[u] = (ushort16)f2bf_rne(W2[k * 64 + j]);
    } else if (t < 14336) {                       // W3: 64x32 -> Wt3: 32x64
        int u = t - 12288; int j = u >> 6, k = u & 63;
        Wt3[u] = (ushort16)f2bf_rne(W3[k * 32 + j]);
    } else if (t < 14592) {                       // batch segments (sorted batch arrays)
        int q = t - 14336;
        const int* bat = (q < 128) ? b1 : b2;
        const int g = q & 127;
        int lo = 0, hi = TOT;
        while (lo < hi) { int m = (lo + hi) >> 1; if (bat[m] < g) lo = m + 1; else hi = m; }
        const int s0 = lo;
        hi = TOT;
        while (lo < hi) { int m = (lo + hi) >> 1; if (bat[m] < g + 1) lo = m + 1; else hi = m; }
        st[q] = s0;
        cnt[q] = lo - s0;
    }
}

// ---------------- edge bucketing: pass A (count + reserve) ----------------
__global__ __launch_bounds__(256) void bktcnt_k(const int* __restrict__ ei1, const int* __restrict__ ei2,
                                                int* __restrict__ gcnt, int* __restrict__ blkbase) {
    __shared__ int hist[NB];
    const int tid = threadIdx.x, blk = blockIdx.x;
#pragma unroll
    for (int q = 0; q < 4; ++q) hist[q * 256 + tid] = 0;
    __syncthreads();
    const long long base = (long long)blk * 8192;
    for (int q = 0; q < 32; ++q) {
        long long e = base + q * 256 + tid;
        int d = (e < Ec) ? ei1[Ec + e] : (TOT + ei2[Ec + (e - Ec)]);
        atomicAdd(&hist[d >> 7], 1);
    }
    __syncthreads();
#pragma unroll
    for (int q = 0; q < 4; ++q) {
        int bb = q * 256 + tid;
        int c = hist[bb];
        int old = atomicAdd(&gcnt[bb], c);
        blkbase[blk * NB + bb] = old;
    }
}

// ---------------- exclusive scan of 1024 bucket counts ----------------
__global__ __launch_bounds__(1024) void scan1024_k(const int* __restrict__ gcnt, int* __restrict__ goff) {
    __shared__ int ws[16];
    const int t = threadIdx.x, lane = t & 63, wid = t >> 6;
    int v = gcnt[t];
    int inc = v;
#pragma unroll
    for (int d = 1; d < 64; d <<= 1) { int n = __shfl_up(inc, d, 64); if (lane >= d) inc += n; }
    if (lane == 63) ws[wid] = inc;
    __syncthreads();
    if (t == 0) { int o = 0; for (int q = 0; q < 16; ++q) { int x = ws[q]; ws[q] = o; o += x; } }
    __syncthreads();
    goff[t] = ws[wid] + inc - v;
    if (t == 1023) goff[NB] = ws[15] + inc;
}

// ---------------- edge bucketing: pass B (scatter into per-block runs) ----------------
// payload: src_global (17b) | dst_local (7b) << 20
__global__ __launch_bounds__(256) void bktfill_k(const int* __restrict__ ei1, const int* __restrict__ ei2,
                                                 const int* __restrict__ goff, const int* __restrict__ blkbase,
                                                 uint32* __restrict__ bkt) {
    __shared__ int hist[NB];
    __shared__ int hbase[NB];
    const int tid = threadIdx.x, blk = blockIdx.x;
#pragma unroll
    for (int q = 0; q < 4; ++q) {
        int bb = q * 256 + tid;
        hist[bb] = 0;
        hbase[bb] = goff[bb] + blkbase[blk * NB + bb];
    }
    __syncthreads();
    const long long base = (long long)blk * 8192;
    for (int q = 0; q < 32; ++q) {
        long long e = base + q * 256 + tid;
        int s, d;
        if (e < Ec) { s = ei1[e]; d = ei1[Ec + e]; }
        else        { long long e2 = e - Ec; s = TOT + ei2[e2]; d = TOT + ei2[Ec + e2]; }
        int bb = d >> 7;
        int lofs = atomicAdd(&hist[bb], 1);
        bkt[hbase[bb] + lofs] = (uint32)s | ((uint32)(d & 127) << 20);
    }
}

// ---------------- per-bucket counting sort by (dst_local, src_octant) ----------------
// -> CSR src lists (octant-ordered per node) + rowptr + dis
__global__ __launch_bounds__(256) void bktsort_k(const int* __restrict__ goff, const uint32* __restrict__ bkt,
                                                 uint32* __restrict__ csr, int* __restrict__ rowptr,
                                                 float* __restrict__ dis) {
    __shared__ int keyc[NKEY];      // counts -> exclusive offsets -> cursors
    __shared__ int wsum[4];
    const int b = blockIdx.x, tid = threadIdx.x;
    const int e0 = goff[b], e1 = goff[b + 1];
    const int ne = e1 - e0;
#pragma unroll
    for (int q = 0; q < 4; ++q) keyc[q * 256 + tid] = 0;
    __syncthreads();
    for (int i = tid; i < ne; i += 256) {
        uint32 v = bkt[e0 + i];
        int dl = v >> 20, src = v & 0x1FFFF;
        atomicAdd(&keyc[dl * 8 + ((src >> 13) & 7)], 1);
    }
    __syncthreads();
    // block-parallel exclusive scan over 1024 keys (each thread owns 4)
    const int lane = tid & 63, wid = tid >> 6;
    int s0 = keyc[tid * 4], s1 = keyc[tid * 4 + 1], s2 = keyc[tid * 4 + 2], s3 = keyc[tid * 4 + 3];
    int tot = s0 + s1 + s2 + s3;
    int inc = tot;
#pragma unroll
    for (int d = 1; d < 64; d <<= 1) { int n = __shfl_up(inc, d, 64); if (lane >= d) inc += n; }
    if (lane == 63) wsum[wid] = inc;
    __syncthreads();
    int wbase = 0;
    for (int q = 0; q < wid; ++q) wbase += wsum[q];
    const int myoff = wbase + inc - tot;
    __syncthreads();
    keyc[tid * 4]     = myoff;
    keyc[tid * 4 + 1] = myoff + s0;
    keyc[tid * 4 + 2] = myoff + s0 + s1;
    keyc[tid * 4 + 3] = myoff + s0 + s1 + s2;
    __syncthreads();
    if (tid < BKN) {
        int off_dl = keyc[tid * 8];
        int nxt = (tid < 127) ? keyc[(tid + 1) * 8] : ne;
        rowptr[b * BKN + tid] = e0 + off_dl;
        dis[b * BKN + tid] = rsqrtf((float)(nxt - off_dl) + 1.0f);
    }
    __syncthreads();
    for (int i = tid; i < ne; i += 256) {
        uint32 v = bkt[e0 + i];
        int dl = v >> 20, src = v & 0x1FFFF;
        int pos = atomicAdd(&keyc[dl * 8 + ((src >> 13) & 7)], 1);
        csr[e0 + pos] = (uint32)src;
    }
    if (b == 0 && tid == 0) rowptr[TOT2] = (int)(2 * Ec);
}

// ---------------- MFMA GEMM: out_bf16[M,NC] = dis[row] * ((relu?)X[M,K] @ W[K,NC]) ----------------
template<int K, int NC, bool RELU, bool XBF>
__global__ __launch_bounds__(256) void gemmf_k(const void* __restrict__ X1v,
                                               const void* __restrict__ X2v,
                                               const ushort16* __restrict__ Wt,   // [NC][K] bf16
                                               const float* __restrict__ dis,
                                               ushort16* __restrict__ out) {
    constexpr int NK = K / 32;
    const int tid = threadIdx.x, lane = tid & 63, wave = tid >> 6;
    const int i0 = (blockIdx.x * 4 + wave) * 16;
    const int arow = i0 + (lane & 15);
    const int ks0 = (lane >> 4) * 8;
    bf16x8 a[NK];
    if (XBF) {
        const uint32* Xr = (arow < TOT) ? (const uint32*)X1v + (size_t)arow * (K / 2)
                                        : (const uint32*)X2v + (size_t)(arow - TOT) * (K / 2);
#pragma unroll
        for (int s = 0; s < NK; ++s) {
            uint4 v = *(const uint4*)(Xr + s * 16 + ks0 / 2);
            if (RELU) { v.x = relu_bf2(v.x); v.y = relu_bf2(v.y); v.z = relu_bf2(v.z); v.w = relu_bf2(v.w); }
            a[s] = *(bf16x8*)&v;
        }
    } else {
        const float* Xr = (arow < TOT) ? (const float*)X1v + (size_t)arow * K
                                       : (const float*)X2v + (size_t)(arow - TOT) * K;
#pragma unroll
        for (int s = 0; s < NK; ++s) {
            float4 v0 = *(const float4*)(Xr + s * 32 + ks0);
            float4 v1 = *(const float4*)(Xr + s * 32 + ks0 + 4);
            if (RELU) {
                v0.x = fmaxf(v0.x, 0.f); v0.y = fmaxf(v0.y, 0.f); v0.z = fmaxf(v0.z, 0.f); v0.w = fmaxf(v0.w, 0.f);
                v1.x = fmaxf(v1.x, 0.f); v1.y = fmaxf(v1.y, 0.f); v1.z = fmaxf(v1.z, 0.f); v1.w = fmaxf(v1.w, 0.f);
            }
            uint4 p;
            p.x = f2bf_rne(v0.x) | (f2bf_rne(v0.y) << 16);
            p.y = f2bf_rne(v0.z) | (f2bf_rne(v0.w) << 16);
            p.z = f2bf_rne(v1.x) | (f2bf_rne(v1.y) << 16);
            p.w = f2bf_rne(v1.z) | (f2bf_rne(v1.w) << 16);
            a[s] = *(bf16x8*)&p;
        }
    }
    float dv[4];
#pragma unroll
    for (int r = 0; r < 4; ++r) dv[r] = dis[i0 + (lane >> 4) * 4 + r];
#pragma unroll
    for (int jt = 0; jt < NC / 16; ++jt) {
        const int col = jt * 16 + (lane & 15);
        f32x4 cc = {0.f, 0.f, 0.f, 0.f};
#pragma unroll
        for (int s = 0; s < NK; ++s) {
            bf16x8 b = *(const bf16x8*)(Wt + (size_t)col * K + s * 32 + ks0);
            cc = __builtin_amdgcn_mfma_f32_16x16x32_bf16(a[s], b, cc, 0, 0, 0);
        }
#pragma unroll
        for (int r = 0; r < 4; ++r) {
            const int row = i0 + (lane >> 4) * 4 + r;
            out[(size_t)row * NC + col] = (ushort16)f2bf_rne(cc[r] * dv[r]);
        }
    }
}

// ---------------- GCN aggregation: unweighted CSR sum of hs rows ----------------
// out_bf16[i] = dis[i] * (hs[i] + sum_e hs[csr[e]]) + bias
// 16-deep load pipeline + XCD side-swizzle; edge lists octant-ordered for L2 phasing.
template<int NC>
__global__ __launch_bounds__(256) void gatherb_k(uint32* __restrict__ out, const uint32* __restrict__ hs,
                                                 const float* __restrict__ dis, const float* __restrict__ bias,
                                                 const int* __restrict__ rowptr, const uint32* __restrict__ csr) {
    constexpr int TPN = NC / 2;
    constexpr int NPB = 256 / TPN;
    int bid;
    {
        const int xcd = blockIdx.x & 7, idx = blockIdx.x >> 3;
        const int half = gridDim.x >> 1;
        bid = (xcd < 4) ? (idx * 4 + xcd) : (half + idx * 4 + (xcd - 4));
    }
    const int tid = threadIdx.x;
    const int cp = tid & (TPN - 1);
    const int node = bid * NPB + tid / TPN;
    const float2 bb = ((const float2*)bias)[cp];
    float2 sv = bf2f(hs[(size_t)node * TPN + cp]);
    float acc0 = sv.x, acc1 = sv.y;
    int e = rowptr[node];
    const int e1 = rowptr[node + 1];
    for (; e + 16 <= e1; e += 16) {
        uint32 p[16];
#pragma unroll
        for (int q = 0; q < 16; ++q) p[q] = hs[(size_t)csr[e + q] * TPN + cp];
#pragma unroll
        for (int q = 0; q < 16; ++q) { float2 f = bf2f(p[q]); acc0 += f.x; acc1 += f.y; }
    }
    if (e + 8 <= e1) {
        uint32 p[8];
#pragma unroll
        for (int q = 0; q < 8; ++q) p[q] = hs[(size_t)csr[e + q] * TPN + cp];
#pragma unroll
        for (int q = 0; q < 8; ++q) { float2 f = bf2f(p[q]); acc0 += f.x; acc1 += f.y; }
        e += 8;
    }
    if (e + 4 <= e1) {
        uint32 p[4];
#pragma unroll
        for (int q = 0; q < 4; ++q) p[q] = hs[(size_t)csr[e + q] * TPN + cp];
#pragma unroll
        for (int q = 0; q < 4; ++q) { float2 f = bf2f(p[q]); acc0 += f.x; acc1 += f.y; }
        e += 4;
    }
    for (; e < e1; ++e) {
        float2 f = bf2f(hs[(size_t)csr[e] * TPN + cp]);
        acc0 += f.x; acc1 += f.y;
    }
    const float dv = dis[node];
    out[(size_t)node * TPN + cp] = f2bf_rne(acc0 * dv + bb.x) | (f2bf_rne(acc1 * dv + bb.y) << 16);
}

// ---------------- attention pooling (bf16 AF input) ----------------
__global__ __launch_bounds__(256) void attpool_k(const ushort16* __restrict__ af,
                                                 const int* __restrict__ cnt, const int* __restrict__ st,
                                                 const float* __restrict__ attW, float* __restrict__ pool) {
    const int side = blockIdx.x >> 7, b = blockIdx.x & 127;
    const ushort16* h = af + (size_t)side * TOT * 32;
    const int c = cnt[side * 128 + b], s0 = st[side * 128 + b];
    const int f = threadIdx.x & 31, grp = threadIdx.x >> 5;
    __shared__ float red[8][32];
    __shared__ float mhS[32], tS[32];
    float acc = 0.f;
    for (int i = grp; i < c; i += 8) acc += bf1f(h[(size_t)(s0 + i) * 32 + f]);
    red[grp][f] = acc;
    __syncthreads();
    if (threadIdx.x < 32) { float tt = 0; for (int g = 0; g < 8; ++g) tt += red[g][f]; mhS[f] = tt / (float)c; }
    __syncthreads();
    if (threadIdx.x < 32) {
        float g = 0;
        for (int k = 0; k < 32; ++k) g += mhS[k] * attW[k * 32 + f];
        tS[f] = tanhf(g);
    }
    __syncthreads();
    const float tf = tS[f];
    acc = 0.f;
    for (int i = grp; i < c; i += 8) {
        float hv = bf1f(h[(size_t)(s0 + i) * 32 + f]);
        float pr = hv * tf;
#pragma unroll
        for (int m = 16; m; m >>= 1) pr += __shfl_xor(pr, m, 32);
        float sA = 1.f / (1.f + expf(-pr));
        acc += hv * sA;
    }
    __syncthreads();
    red[grp][f] = acc;
    __syncthreads();
    if (threadIdx.x < 32) {
        float tt = 0; for (int g = 0; g < 8; ++g) tt += red[g][f];
        pool[(size_t)(side * 128 + b) * 32 + f] = tt;
    }
}

// ---------------- histogram pass 1: MFMA min/max of raw dots ----------------
__global__ __launch_bounds__(256) void mm2_k(const ushort16* __restrict__ afb,
                                             const int* __restrict__ cnt, const int* __restrict__ st,
                                             float* __restrict__ bmn, float* __restrict__ bmx) {
    const int b = blockIdx.x >> 3, it8 = blockIdx.x & 7;
    const int c1 = cnt[b], c2 = cnt[128 + b];
    const int s1 = st[b], s2 = st[128 + b];
    const int nn = max(c1, c2);
    const int tid = threadIdx.x, lane = tid & 63, wave = tid >> 6;
    const int itile = it8 * 4 + wave;
    const int i0 = itile * 16;
    float lmn = 1e30f, lmx = -1e30f;
    if (i0 < nn) {
        const int arow = i0 + (lane & 15);
        const int koff = (lane >> 4) * 8;
        bf16x8 a = {0, 0, 0, 0, 0, 0, 0, 0};
        if (arow < c1) a = *(const bf16x8*)(afb + (size_t)(s1 + arow) * 32 + koff);
        const int ibase = i0 + (lane >> 4) * 4;
        const int njt = (nn + 15) >> 4;
        for (int jt = 0; jt < njt; ++jt) {
            const int brow = jt * 16 + (lane & 15);
            bf16x8 bb = {0, 0, 0, 0, 0, 0, 0, 0};
            if (brow < c2) bb = *(const bf16x8*)(afb + (size_t)(s2 + brow) * 32 + koff);
            f32x4 cc = {0.f, 0.f, 0.f, 0.f};
            cc = __builtin_amdgcn_mfma_f32_16x16x32_bf16(a, bb, cc, 0, 0, 0);
            if (brow < nn) {
#pragma unroll
                for (int r = 0; r < 4; ++r) {
                    if (ibase + r < nn) { lmn = fminf(lmn, cc[r]); lmx = fmaxf(lmx, cc[r]); }
                }
            }
        }
    }
    __shared__ float redn[256], redx[256];
    redn[tid] = lmn; redx[tid] = lmx;
    __syncthreads();
    for (int sr = 128; sr; sr >>= 1) {
        if (tid < sr) {
            redn[tid] = fminf(redn[tid], redn[tid + sr]);
            redx[tid] = fmaxf(redx[tid], redx[tid + sr]);
        }
        __syncthreads();
    }
    if (tid == 0) { bmn[blockIdx.x] = redn[0]; bmx[blockIdx.x] = redx[0]; }
}

// ---------------- histogram pass 2: MFMA + bin ----------------
__global__ __launch_bounds__(256) void bin2_k(const ushort16* __restrict__ afb,
                                              const int* __restrict__ cnt, const int* __restrict__ st,
                                              const float* __restrict__ bmn, const float* __restrict__ bmx,
                                              float* __restrict__ hist) {
    const int b = blockIdx.x >> 3, it8 = blockIdx.x & 7;
    const int c1 = cnt[b], c2 = cnt[128 + b];
    const int s1 = st[b], s2 = st[128 + b];
    const int nn = max(c1, c2);
    const int tid = threadIdx.x, lane = tid & 63, wave = tid >> 6;
    const int itile = it8 * 4 + wave;
    const int i0 = itile * 16;
    float dmn = 1e30f, dmx = -1e30f;
#pragma unroll
    for (int q = 0; q < 8; ++q) {
        dmn = fminf(dmn, bmn[(b << 3) + q]);
        dmx = fmaxf(dmx, bmx[(b << 3) + q]);
    }
    const float vMn = sigm(dmn), vMx = sigm(dmx);
    const float vScale = 16.f / ((vMx > vMn) ? (vMx - vMn) : 1.f);
    __shared__ int hloc[16 * 256];
    __shared__ int part[64];
#pragma unroll
    for (int q = 0; q < 16; ++q) hloc[q * 256 + tid] = 0;
    __syncthreads();
    if (i0 < nn) {
        const int arow = i0 + (lane & 15);
        const int koff = (lane >> 4) * 8;
        bf16x8 a = {0, 0, 0, 0, 0, 0, 0, 0};
        if (arow < c1) a = *(const bf16x8*)(afb + (size_t)(s1 + arow) * 32 + koff);
        const int ibase = i0 + (lane >> 4) * 4;
        const int njt = (nn + 15) >> 4;
        for (int jt = 0; jt < njt; ++jt) {
            const int brow = jt * 16 + (lane & 15);
            bf16x8 bb = {0, 0, 0, 0, 0, 0, 0, 0};
            if (brow < c2) bb = *(const bf16x8*)(afb + (size_t)(s2 + brow) * 32 + koff);
            f32x4 cc = {0.f, 0.f, 0.f, 0.f};
            cc = __builtin_amdgcn_mfma_f32_16x16x32_bf16(a, bb, cc, 0, 0, 0);
            if (brow < nn) {
#pragma unroll
                for (int r = 0; r < 4; ++r) {
                    if (ibase + r < nn) {
                        float t = (sigm(cc[r]) - vMn) * vScale;
                        int bi = (int)floorf(t);
                        bi = bi < 0 ? 0 : (bi > 15 ? 15 : bi);
                        hloc[bi * 256 + tid] += 1;
                    }
                }
            }
        }
    }
    __syncthreads();
    if (tid < 64) {
        const int bin = tid & 15, q = tid >> 4;
        int s = 0;
        for (int t2 = q * 64; t2 < q * 64 + 64; ++t2) s += hloc[bin * 256 + t2];
        part[tid] = s;
    }
    __syncthreads();
    if (tid < 16) {
        int s = part[tid] + part[16 + tid] + part[32 + tid] + part[48 + tid];
        atomicAdd(&hist[b * 16 + tid], (float)s);
    }
}

// ---------------- NTN + final MLP (one block per graph) ----------------
__global__ __launch_bounds__(64) void final_k(const float* __restrict__ pool, const float* __restrict__ hist,
                                              const int* __restrict__ cnt,
                                              const float* __restrict__ ntnW, const float* __restrict__ ntnV,
                                              const float* __restrict__ ntnb, const float* __restrict__ fc1W,
                                              const float* __restrict__ fc1b, const float* __restrict__ scW,
                                              const float* __restrict__ scb, float* __restrict__ out) {
    const int b = blockIdx.x;
    const int tid = threadIdx.x;
    __shared__ float P1[32], P2[32], feat[32], red[64];
    if (tid < 32) { P1[tid] = pool[b * 32 + tid]; P2[tid] = pool[4096 + b * 32 + tid]; }
    __syncthreads();
    const int k = tid & 15, part = tid >> 4;
    float acc = 0.f;
    for (int i = part * 8; i < part * 8 + 8; ++i) {
        float p1i = P1[i];
        for (int j = 0; j < 32; ++j) acc += p1i * P2[j] * ntnW[(i * 32 + j) * 16 + k];
    }
    red[tid] = acc;
    __syncthreads();
    if (tid < 16) {
        float bl = red[tid] + red[16 + tid] + red[32 + tid] + red[48 + tid];
        float blk = ntnb[tid];
        for (int i = 0; i < 32; ++i) blk += P1[i] * ntnV[tid * 64 + i];
        for (int j = 0; j < 32; ++j) blk += P2[j] * ntnV[tid * 64 + 32 + j];
        feat[tid] = fmaxf(bl + blk, 0.f);
        const int nn = max(cnt[b], cnt[128 + b]);
        feat[16 + tid] = hist[b * 16 + tid] / (float)(nn * nn);
    }
    __syncthreads();
    if (tid < 16) {
        float h = fc1b[tid];
        for (int f = 0; f < 32; ++f) h += feat[f] * fc1W[f * 16 + tid];
        red[tid] = fmaxf(h, 0.f);
    }
    __syncthreads();
    if (tid == 0) {
        float o = scb[0];
        for (int j = 0; j < 16; ++j) o += red[j] * scW[j];
        out[b] = 1.f / (1.f + expf(-o));
    }
}

// ---------------- launch ----------------
extern "C" void kernel_launch(void* const* d_in, const int* in_sizes, int n_in,
                              void* d_out, int out_size, void* d_ws, size_t ws_size,
                              hipStream_t stream) {
    const float* x1   = (const float*)d_in[0];
    const float* x2   = (const float*)d_in[1];
    const int*   ei1  = (const int*)d_in[2];
    const int*   ei2  = (const int*)d_in[3];
    const int*   bat1 = (const int*)d_in[4];
    const int*   bat2 = (const int*)d_in[5];
    const float* W1   = (const float*)d_in[6];
    const float* b1   = (const float*)d_in[7];
    const float* W2   = (const float*)d_in[8];
    const float* b2   = (const float*)d_in[9];
    const float* W3   = (const float*)d_in[10];
    const float* b3   = (const float*)d_in[11];
    const float* attW = (const float*)d_in[12];
    const float* ntnW = (const float*)d_in[13];
    const float* ntnV = (const float*)d_in[14];
    const float* ntnb = (const float*)d_in[15];
    const float* fc1W = (const float*)d_in[16];
    const float* fc1b = (const float*)d_in[17];
    const float* scW  = (const float*)d_in[18];
    const float* scb  = (const float*)d_in[19];
    float* out = (float*)d_out;

    // workspace layout (~64 MB)
    uint32* Hbuf  = (uint32*)d_ws;                       // hs rows: 131072*32 u32 (16.8 MB)
    uint32* Gb    = Hbuf + (size_t)TOT2 * 32;            // activations: 131072*32 u32 (16.8 MB)
    uint32* AFb   = Gb + (size_t)TOT2 * 32;              // AF: 131072*16 u32 (8.4 MB)
    uint32* bkt   = AFb + (size_t)TOT2 * 16;             // bucket-grouped edges: 2M u32 (8.4 MB)
    uint32* csr   = bkt + 2 * (size_t)Ec;                // CSR src lists: 2M u32 (8.4 MB)
    float* dis    = (float*)(csr + 2 * (size_t)Ec);      // 131072
    int*   rowptr = (int*)(dis + TOT2);                  // 131073
    int*   gcnt   = rowptr + TOT2 + 1;                   // 1024
    int*   goff   = gcnt + NB;                           // 1025
    int*   blkbase= goff + NB + 1;                       // 256*1024 (1 MB)
    int*   cnt    = blkbase + 256 * NB;                  // 256
    int*   st     = cnt + 256;                           // 256
    float* pool   = (float*)(st + 256);                  // 8192
    float* hist   = pool + 8192;                         // 2048
    float* bmn    = hist + 2048;                         // 1024
    float* bmx    = bmn + 1024;                          // 1024
    ushort16* Wt1 = (ushort16*)(bmx + 1024);             // 64*128 bf16
    ushort16* Wt2 = Wt1 + 8192;                          // 64*64
    ushort16* Wt3 = Wt2 + 4096;                          // 32*64

    hipMemsetAsync(gcnt, 0, NB * sizeof(int), stream);
    hipMemsetAsync(hist, 0, 2048 * sizeof(float), stream);
    setup_k<<<57, 256, 0, stream>>>(W1, W2, W3, Wt1, Wt2, Wt3, bat1, bat2, cnt, st);
    bktcnt_k<<<256, 256, 0, stream>>>(ei1, ei2, gcnt, blkbase);
    scan1024_k<<<1, 1024, 0, stream>>>(gcnt, goff);
    bktfill_k<<<256, 256, 0, stream>>>(ei1, ei2, goff, blkbase, bkt);
    bktsort_k<<<NB, 256, 0, stream>>>(goff, bkt, csr, rowptr, dis);

    // Layer 1 (K=128 f32 -> hs bf16), MFMA
    gemmf_k<128, 64, false, false><<<2048, 256, 0, stream>>>(x1, x2, Wt1, dis, (ushort16*)Hbuf);
    gatherb_k<64><<<TOT2 / 8, 256, 0, stream>>>(Gb, Hbuf, dis, b1, rowptr, csr);

    // Layer 2 (64 -> 64), relu fused into A-fragment load
    gemmf_k<64, 64, true, true><<<2048, 256, 0, stream>>>(Gb, Gb, Wt2, dis, (ushort16*)Hbuf);
    gatherb_k<64><<<TOT2 / 8, 256, 0, stream>>>(Gb, Hbuf, dis, b2, rowptr, csr);

    // Layer 3 (64 -> 32)
    gemmf_k<64, 32, true, true><<<2048, 256, 0, stream>>>(Gb, Gb, Wt3, dis, (ushort16*)Hbuf);
    gatherb_k<32><<<TOT2 / 16, 256, 0, stream>>>(AFb, Hbuf, dis, b3, rowptr, csr);

    // Pooling, histogram, head
    attpool_k<<<256, 256, 0, stream>>>((const ushort16*)AFb, cnt, st, attW, pool);
    mm2_k<<<1024, 256, 0, stream>>>((const ushort16*)AFb, cnt, st, bmn, bmx);
    bin2_k<<<1024, 256, 0, stream>>>((const ushort16*)AFb, cnt, st, bmn, bmx, hist);
    final_k<<<128, 64, 0, stream>>>(pool, hist, cnt, ntnW, ntnV, ntnb, fc1W, fc1b, scW, scb, out);
}

// Round 13
// 329.187 us; speedup vs baseline: 6.0219x; 1.0833x over previous
//
#include <hip/hip_runtime.h>
#include <hip/hip_bf16.h>

// Problem constants (fixed by setup_inputs)
constexpr int    TOT = 65536;        // nodes per side
constexpr int    TOT2 = 131072;      // both sides
constexpr long long Ec = 16LL * TOT; // 1048576 edges per side
constexpr int    NB  = 1024;         // dst buckets (128 nodes each)
constexpr int    BKN = 128;          // nodes per bucket
constexpr int    CAP = 2560;         // bucket capacity (mean 2048, +11 sigma)
constexpr int    NKEY = 1024;        // counting-sort keys: 128 dl x 8 src-octants

typedef unsigned int   uint32;
typedef unsigned short ushort16;
typedef __attribute__((ext_vector_type(8))) short bf16x8;
typedef __attribute__((ext_vector_type(4))) float f32x4;

__device__ __forceinline__ float sigm(float x) { return 1.f / (1.f + __expf(-x)); }

__device__ __forceinline__ uint32 f2bf_rne(float x) {
    uint32 u = __float_as_uint(x);
    return (u + 0x7fffu + ((u >> 16) & 1u)) >> 16;
}
__device__ __forceinline__ float2 bf2f(uint32 u) {
    return make_float2(__uint_as_float(u << 16), __uint_as_float(u & 0xffff0000u));
}
__device__ __forceinline__ float bf1f(ushort16 u) {
    return __uint_as_float(((uint32)u) << 16);
}
__device__ __forceinline__ uint32 relu_bf2(uint32 v) {
    uint32 keep = (((int)v < 0) ? 0u : 0xFFFF0000u) | ((v & 0x8000u) ? 0u : 0x0000FFFFu);
    return v & keep;
}

// ---------------- setup: weight transpose/convert + batch segments ----------------
__global__ void setup_k(const float* __restrict__ W1, const float* __restrict__ W2,
                        const float* __restrict__ W3, ushort16* __restrict__ Wt1,
                        ushort16* __restrict__ Wt2, ushort16* __restrict__ Wt3,
                        const int* __restrict__ b1, const int* __restrict__ b2,
                        int* __restrict__ cnt, int* __restrict__ st) {
    int t = blockIdx.x * 256 + threadIdx.x;
    if (t < 8192) {                               // W1: 128x64 -> Wt1: 64x128
        int j = t >> 7, k = t & 127;
        Wt1[t] = (ushort16)f2bf_rne(W1[k * 64 + j]);
    } else if (t < 12288) {                       // W2: 64x64 -> Wt2: 64x64
        int u = t - 8192; int j = u >> 6, k = u & 63;
        Wt2[u] = (ushort16)f2bf_rne(W2[k * 64 + j]);
    } else if (t < 14336) {                       // W3: 64x32 -> Wt3: 32x64
        int u = t - 12288; int j = u >> 6, k = u & 63;
        Wt3[u] = (ushort16)f2bf_rne(W3[k * 32 + j]);
    } else if (t < 14592) {                       // batch segments (sorted batch arrays)
        int q = t - 14336;
        const int* bat = (q < 128) ? b1 : b2;
        const int g = q & 127;
        int lo = 0, hi = TOT;
        while (lo < hi) { int m = (lo + hi) >> 1; if (bat[m] < g) lo = m + 1; else hi = m; }
        const int s0 = lo;
        hi = TOT;
        while (lo < hi) { int m = (lo + hi) >> 1; if (bat[m] < g + 1) lo = m + 1; else hi = m; }
        st[q] = s0;
        cnt[q] = lo - s0;
    }
}

// ---------------- edge bucketing (single pass): count, reserve, scatter ----------------
// Fixed-capacity strided buckets: bucket bb owns bkt[bb*CAP .. bb*CAP+gcnt[bb]).
// payload: src_global (17b) | dst_local (7b) << 20
__global__ __launch_bounds__(256) void bktfill2_k(const int* __restrict__ ei1, const int* __restrict__ ei2,
                                                  int* __restrict__ gcnt, uint32* __restrict__ bkt) {
    __shared__ int hist[NB];
    __shared__ int hbase[NB];
    const int tid = threadIdx.x, blk = blockIdx.x;
#pragma unroll
    for (int q = 0; q < 4; ++q) hist[q * 256 + tid] = 0;
    __syncthreads();
    const long long base = (long long)blk * 8192;
    for (int q = 0; q < 32; ++q) {
        long long e = base + q * 256 + tid;
        int d = (e < Ec) ? ei1[Ec + e] : (TOT + ei2[Ec + (e - Ec)]);
        atomicAdd(&hist[d >> 7], 1);
    }
    __syncthreads();
#pragma unroll
    for (int q = 0; q < 4; ++q) {
        int bb = q * 256 + tid;
        int c = hist[bb];
        hbase[bb] = c ? atomicAdd(&gcnt[bb], c) : 0;
        hist[bb] = 0;
    }
    __syncthreads();
    for (int q = 0; q < 32; ++q) {
        long long e = base + q * 256 + tid;
        int s, d;
        if (e < Ec) { s = ei1[e]; d = ei1[Ec + e]; }
        else        { long long e2 = e - Ec; s = TOT + ei2[e2]; d = TOT + ei2[Ec + e2]; }
        int bb = d >> 7;
        int lofs = atomicAdd(&hist[bb], 1);
        bkt[(size_t)bb * CAP + hbase[bb] + lofs] = (uint32)s | ((uint32)(d & 127) << 20);
    }
}

// ---------------- per-bucket counting sort by (dst_local, src_octant) ----------------
// -> CSR src lists (strided regions) + rowstart/rowend + dis
__global__ __launch_bounds__(256) void bktsort_k(const int* __restrict__ gcnt, const uint32* __restrict__ bkt,
                                                 uint32* __restrict__ csr, int* __restrict__ rowstart,
                                                 int* __restrict__ rowend, float* __restrict__ dis) {
    __shared__ int keyc[NKEY];      // counts -> exclusive offsets -> cursors
    __shared__ int wsum[4];
    const int b = blockIdx.x, tid = threadIdx.x;
    const int ne = gcnt[b];
    const int e0 = b * CAP;
#pragma unroll
    for (int q = 0; q < 4; ++q) keyc[q * 256 + tid] = 0;
    __syncthreads();
    for (int i = tid; i < ne; i += 256) {
        uint32 v = bkt[e0 + i];
        int dl = v >> 20, src = v & 0x1FFFF;
        atomicAdd(&keyc[dl * 8 + ((src >> 13) & 7)], 1);
    }
    __syncthreads();
    const int lane = tid & 63, wid = tid >> 6;
    int s0 = keyc[tid * 4], s1 = keyc[tid * 4 + 1], s2 = keyc[tid * 4 + 2], s3 = keyc[tid * 4 + 3];
    int tot = s0 + s1 + s2 + s3;
    int inc = tot;
#pragma unroll
    for (int d = 1; d < 64; d <<= 1) { int n = __shfl_up(inc, d, 64); if (lane >= d) inc += n; }
    if (lane == 63) wsum[wid] = inc;
    __syncthreads();
    int wbase = 0;
    for (int q = 0; q < wid; ++q) wbase += wsum[q];
    const int myoff = wbase + inc - tot;
    __syncthreads();
    keyc[tid * 4]     = myoff;
    keyc[tid * 4 + 1] = myoff + s0;
    keyc[tid * 4 + 2] = myoff + s0 + s1;
    keyc[tid * 4 + 3] = myoff + s0 + s1 + s2;
    __syncthreads();
    if (tid < BKN) {
        int off_dl = keyc[tid * 8];
        int nxt = (tid < 127) ? keyc[(tid + 1) * 8] : ne;
        rowstart[b * BKN + tid] = e0 + off_dl;
        rowend[b * BKN + tid]   = e0 + nxt;
        dis[b * BKN + tid] = rsqrtf((float)(nxt - off_dl) + 1.0f);
    }
    __syncthreads();
    for (int i = tid; i < ne; i += 256) {
        uint32 v = bkt[e0 + i];
        int dl = v >> 20, src = v & 0x1FFFF;
        int pos = atomicAdd(&keyc[dl * 8 + ((src >> 13) & 7)], 1);
        csr[e0 + pos] = (uint32)src;
    }
}

// ---------------- MFMA GEMM: out_bf16[M,NC] = dis[row] * ((relu?)X[M,K] @ W[K,NC]) ----------------
template<int K, int NC, bool RELU, bool XBF>
__global__ __launch_bounds__(256) void gemmf_k(const void* __restrict__ X1v,
                                               const void* __restrict__ X2v,
                                               const ushort16* __restrict__ Wt,   // [NC][K] bf16
                                               const float* __restrict__ dis,
                                               ushort16* __restrict__ out) {
    constexpr int NK = K / 32;
    const int tid = threadIdx.x, lane = tid & 63, wave = tid >> 6;
    const int i0 = (blockIdx.x * 4 + wave) * 16;
    const int arow = i0 + (lane & 15);
    const int ks0 = (lane >> 4) * 8;
    bf16x8 a[NK];
    if (XBF) {
        const uint32* Xr = (arow < TOT) ? (const uint32*)X1v + (size_t)arow * (K / 2)
                                        : (const uint32*)X2v + (size_t)(arow - TOT) * (K / 2);
#pragma unroll
        for (int s = 0; s < NK; ++s) {
            uint4 v = *(const uint4*)(Xr + s * 16 + ks0 / 2);
            if (RELU) { v.x = relu_bf2(v.x); v.y = relu_bf2(v.y); v.z = relu_bf2(v.z); v.w = relu_bf2(v.w); }
            a[s] = *(bf16x8*)&v;
        }
    } else {
        const float* Xr = (arow < TOT) ? (const float*)X1v + (size_t)arow * K
                                       : (const float*)X2v + (size_t)(arow - TOT) * K;
#pragma unroll
        for (int s = 0; s < NK; ++s) {
            float4 v0 = *(const float4*)(Xr + s * 32 + ks0);
            float4 v1 = *(const float4*)(Xr + s * 32 + ks0 + 4);
            if (RELU) {
                v0.x = fmaxf(v0.x, 0.f); v0.y = fmaxf(v0.y, 0.f); v0.z = fmaxf(v0.z, 0.f); v0.w = fmaxf(v0.w, 0.f);
                v1.x = fmaxf(v1.x, 0.f); v1.y = fmaxf(v1.y, 0.f); v1.z = fmaxf(v1.z, 0.f); v1.w = fmaxf(v1.w, 0.f);
            }
            uint4 p;
            p.x = f2bf_rne(v0.x) | (f2bf_rne(v0.y) << 16);
            p.y = f2bf_rne(v0.z) | (f2bf_rne(v0.w) << 16);
            p.z = f2bf_rne(v1.x) | (f2bf_rne(v1.y) << 16);
            p.w = f2bf_rne(v1.z) | (f2bf_rne(v1.w) << 16);
            a[s] = *(bf16x8*)&p;
        }
    }
    float dv[4];
#pragma unroll
    for (int r = 0; r < 4; ++r) dv[r] = dis[i0 + (lane >> 4) * 4 + r];
#pragma unroll
    for (int jt = 0; jt < NC / 16; ++jt) {
        const int col = jt * 16 + (lane & 15);
        f32x4 cc = {0.f, 0.f, 0.f, 0.f};
#pragma unroll
        for (int s = 0; s < NK; ++s) {
            bf16x8 b = *(const bf16x8*)(Wt + (size_t)col * K + s * 32 + ks0);
            cc = __builtin_amdgcn_mfma_f32_16x16x32_bf16(a[s], b, cc, 0, 0, 0);
        }
#pragma unroll
        for (int r = 0; r < 4; ++r) {
            const int row = i0 + (lane >> 4) * 4 + r;
            out[(size_t)row * NC + col] = (ushort16)f2bf_rne(cc[r] * dv[r]);
        }
    }
}

// ---------------- GCN aggregation: unweighted CSR sum of hs rows ----------------
// out_bf16[i] = dis[i] * (hs[i] + sum_e hs[csr[e]]) + bias
// TWO nodes per thread (independent load chains) + 8-deep pipelining + XCD side-swizzle.
template<int NC>
__global__ __launch_bounds__(256) void gatherb_k(uint32* __restrict__ out, const uint32* __restrict__ hs,
                                                 const float* __restrict__ dis, const float* __restrict__ bias,
                                                 const int* __restrict__ rowstart, const int* __restrict__ rowend,
                                                 const uint32* __restrict__ csr) {
    constexpr int TPN = NC / 2;
    constexpr int NG  = 256 / TPN;          // node-groups per block
    constexpr int NPB = 2 * NG;             // nodes per block
    int bid;
    {
        const int xcd = blockIdx.x & 7, idx = blockIdx.x >> 3;
        const int half = gridDim.x >> 1;
        bid = (xcd < 4) ? (idx * 4 + xcd) : (half + idx * 4 + (xcd - 4));
    }
    const int tid = threadIdx.x;
    const int cp = tid & (TPN - 1);
    const int g = tid / TPN;
    const int nodeA = bid * NPB + g;
    const int nodeB = nodeA + NG;
    const float2 bb = ((const float2*)bias)[cp];
    float2 svA = bf2f(hs[(size_t)nodeA * TPN + cp]);
    float2 svB = bf2f(hs[(size_t)nodeB * TPN + cp]);
    float a0 = svA.x, a1 = svA.y;
    float b0 = svB.x, b1 = svB.y;
    int eA = rowstart[nodeA]; const int eA1 = rowend[nodeA];
    int eB = rowstart[nodeB]; const int eB1 = rowend[nodeB];
    // interleaved 8-deep pipelines, two independent chains
    while (true) {
        const bool ca = (eA + 8 <= eA1), cb = (eB + 8 <= eB1);
        if (!ca && !cb) break;
        uint32 pa[8], pb[8];
        if (ca) {
#pragma unroll
            for (int q = 0; q < 8; ++q) pa[q] = hs[(size_t)csr[eA + q] * TPN + cp];
        }
        if (cb) {
#pragma unroll
            for (int q = 0; q < 8; ++q) pb[q] = hs[(size_t)csr[eB + q] * TPN + cp];
        }
        if (ca) {
#pragma unroll
            for (int q = 0; q < 8; ++q) { float2 f = bf2f(pa[q]); a0 += f.x; a1 += f.y; }
            eA += 8;
        }
        if (cb) {
#pragma unroll
            for (int q = 0; q < 8; ++q) { float2 f = bf2f(pb[q]); b0 += f.x; b1 += f.y; }
            eB += 8;
        }
    }
    // tails
    if (eA + 4 <= eA1) {
        uint32 p[4];
#pragma unroll
        for (int q = 0; q < 4; ++q) p[q] = hs[(size_t)csr[eA + q] * TPN + cp];
#pragma unroll
        for (int q = 0; q < 4; ++q) { float2 f = bf2f(p[q]); a0 += f.x; a1 += f.y; }
        eA += 4;
    }
    for (; eA < eA1; ++eA) { float2 f = bf2f(hs[(size_t)csr[eA] * TPN + cp]); a0 += f.x; a1 += f.y; }
    if (eB + 4 <= eB1) {
        uint32 p[4];
#pragma unroll
        for (int q = 0; q < 4; ++q) p[q] = hs[(size_t)csr[eB + q] * TPN + cp];
#pragma unroll
        for (int q = 0; q < 4; ++q) { float2 f = bf2f(p[q]); b0 += f.x; b1 += f.y; }
        eB += 4;
    }
    for (; eB < eB1; ++eB) { float2 f = bf2f(hs[(size_t)csr[eB] * TPN + cp]); b0 += f.x; b1 += f.y; }
    const float dvA = dis[nodeA], dvB = dis[nodeB];
    out[(size_t)nodeA * TPN + cp] = f2bf_rne(a0 * dvA + bb.x) | (f2bf_rne(a1 * dvA + bb.y) << 16);
    out[(size_t)nodeB * TPN + cp] = f2bf_rne(b0 * dvB + bb.x) | (f2bf_rne(b1 * dvB + bb.y) << 16);
}

// ---------------- attention pooling (bf16 AF input) ----------------
__global__ __launch_bounds__(256) void attpool_k(const ushort16* __restrict__ af,
                                                 const int* __restrict__ cnt, const int* __restrict__ st,
                                                 const float* __restrict__ attW, float* __restrict__ pool) {
    const int side = blockIdx.x >> 7, b = blockIdx.x & 127;
    const ushort16* h = af + (size_t)side * TOT * 32;
    const int c = cnt[side * 128 + b], s0 = st[side * 128 + b];
    const int f = threadIdx.x & 31, grp = threadIdx.x >> 5;
    __shared__ float red[8][32];
    __shared__ float mhS[32], tS[32];
    float acc = 0.f;
    for (int i = grp; i < c; i += 8) acc += bf1f(h[(size_t)(s0 + i) * 32 + f]);
    red[grp][f] = acc;
    __syncthreads();
    if (threadIdx.x < 32) { float tt = 0; for (int g = 0; g < 8; ++g) tt += red[g][f]; mhS[f] = tt / (float)c; }
    __syncthreads();
    if (threadIdx.x < 32) {
        float g = 0;
        for (int k = 0; k < 32; ++k) g += mhS[k] * attW[k * 32 + f];
        tS[f] = tanhf(g);
    }
    __syncthreads();
    const float tf = tS[f];
    acc = 0.f;
    for (int i = grp; i < c; i += 8) {
        float hv = bf1f(h[(size_t)(s0 + i) * 32 + f]);
        float pr = hv * tf;
#pragma unroll
        for (int m = 16; m; m >>= 1) pr += __shfl_xor(pr, m, 32);
        float sA = 1.f / (1.f + expf(-pr));
        acc += hv * sA;
    }
    __syncthreads();
    red[grp][f] = acc;
    __syncthreads();
    if (threadIdx.x < 32) {
        float tt = 0; for (int g = 0; g < 8; ++g) tt += red[g][f];
        pool[(size_t)(side * 128 + b) * 32 + f] = tt;
    }
}

// ---------------- histogram pass 1: MFMA min/max of raw dots ----------------
__global__ __launch_bounds__(256) void mm2_k(const ushort16* __restrict__ afb,
                                             const int* __restrict__ cnt, const int* __restrict__ st,
                                             float* __restrict__ bmn, float* __restrict__ bmx) {
    const int b = blockIdx.x >> 3, it8 = blockIdx.x & 7;
    const int c1 = cnt[b], c2 = cnt[128 + b];
    const int s1 = st[b], s2 = st[128 + b];
    const int nn = max(c1, c2);
    const int tid = threadIdx.x, lane = tid & 63, wave = tid >> 6;
    const int itile = it8 * 4 + wave;
    const int i0 = itile * 16;
    float lmn = 1e30f, lmx = -1e30f;
    if (i0 < nn) {
        const int arow = i0 + (lane & 15);
        const int koff = (lane >> 4) * 8;
        bf16x8 a = {0, 0, 0, 0, 0, 0, 0, 0};
        if (arow < c1) a = *(const bf16x8*)(afb + (size_t)(s1 + arow) * 32 + koff);
        const int ibase = i0 + (lane >> 4) * 4;
        const int njt = (nn + 15) >> 4;
        for (int jt = 0; jt < njt; ++jt) {
            const int brow = jt * 16 + (lane & 15);
            bf16x8 bb = {0, 0, 0, 0, 0, 0, 0, 0};
            if (brow < c2) bb = *(const bf16x8*)(afb + (size_t)(s2 + brow) * 32 + koff);
            f32x4 cc = {0.f, 0.f, 0.f, 0.f};
            cc = __builtin_amdgcn_mfma_f32_16x16x32_bf16(a, bb, cc, 0, 0, 0);
            if (brow < nn) {
#pragma unroll
                for (int r = 0; r < 4; ++r) {
                    if (ibase + r < nn) { lmn = fminf(lmn, cc[r]); lmx = fmaxf(lmx, cc[r]); }
                }
            }
        }
    }
    __shared__ float redn[256], redx[256];
    redn[tid] = lmn; redx[tid] = lmx;
    __syncthreads();
    for (int sr = 128; sr; sr >>= 1) {
        if (tid < sr) {
            redn[tid] = fminf(redn[tid], redn[tid + sr]);
            redx[tid] = fmaxf(redx[tid], redx[tid + sr]);
        }
        __syncthreads();
    }
    if (tid == 0) { bmn[blockIdx.x] = redn[0]; bmx[blockIdx.x] = redx[0]; }
}

// ---------------- histogram pass 2: MFMA + bin ----------------
__global__ __launch_bounds__(256) void bin2_k(const ushort16* __restrict__ afb,
                                              const int* __restrict__ cnt, const int* __restrict__ st,
                                              const float* __restrict__ bmn, const float* __restrict__ bmx,
                                              float* __restrict__ hist) {
    const int b = blockIdx.x >> 3, it8 = blockIdx.x & 7;
    const int c1 = cnt[b], c2 = cnt[128 + b];
    const int s1 = st[b], s2 = st[128 + b];
    const int nn = max(c1, c2);
    const int tid = threadIdx.x, lane = tid & 63, wave = tid >> 6;
    const int itile = it8 * 4 + wave;
    const int i0 = itile * 16;
    float dmn = 1e30f, dmx = -1e30f;
#pragma unroll
    for (int q = 0; q < 8; ++q) {
        dmn = fminf(dmn, bmn[(b << 3) + q]);
        dmx = fmaxf(dmx, bmx[(b << 3) + q]);
    }
    const float vMn = sigm(dmn), vMx = sigm(dmx);
    const float vScale = 16.f / ((vMx > vMn) ? (vMx - vMn) : 1.f);
    __shared__ int hloc[16 * 256];
    __shared__ int part[64];
#pragma unroll
    for (int q = 0; q < 16; ++q) hloc[q * 256 + tid] = 0;
    __syncthreads();
    if (i0 < nn) {
        const int arow = i0 + (lane & 15);
        const int koff = (lane >> 4) * 8;
        bf16x8 a = {0, 0, 0, 0, 0, 0, 0, 0};
        if (arow < c1) a = *(const bf16x8*)(afb + (size_t)(s1 + arow) * 32 + koff);
        const int ibase = i0 + (lane >> 4) * 4;
        const int njt = (nn + 15) >> 4;
        for (int jt = 0; jt < njt; ++jt) {
            const int brow = jt * 16 + (lane & 15);
            bf16x8 bb = {0, 0, 0, 0, 0, 0, 0, 0};
            if (brow < c2) bb = *(const bf16x8*)(afb + (size_t)(s2 + brow) * 32 + koff);
            f32x4 cc = {0.f, 0.f, 0.f, 0.f};
            cc = __builtin_amdgcn_mfma_f32_16x16x32_bf16(a, bb, cc, 0, 0, 0);
            if (brow < nn) {
#pragma unroll
                for (int r = 0; r < 4; ++r) {
                    if (ibase + r < nn) {
                        float t = (sigm(cc[r]) - vMn) * vScale;
                        int bi = (int)floorf(t);
                        bi = bi < 0 ? 0 : (bi > 15 ? 15 : bi);
                        hloc[bi * 256 + tid] += 1;
                    }
                }
            }
        }
    }
    __syncthreads();
    if (tid < 64) {
        const int bin = tid & 15, q = tid >> 4;
        int s = 0;
        for (int t2 = q * 64; t2 < q * 64 + 64; ++t2) s += hloc[bin * 256 + t2];
        part[tid] = s;
    }
    __syncthreads();
    if (tid < 16) {
        int s = part[tid] + part[16 + tid] + part[32 + tid] + part[48 + tid];
        atomicAdd(&hist[b * 16 + tid], (float)s);
    }
}

// ---------------- NTN + final MLP (one block per graph) ----------------
__global__ __launch_bounds__(64) void final_k(const float* __restrict__ pool, const float* __restrict__ hist,
                                              const int* __restrict__ cnt,
                                              const float* __restrict__ ntnW, const float* __restrict__ ntnV,
                                              const float* __restrict__ ntnb, const float* __restrict__ fc1W,
                                              const float* __restrict__ fc1b, const float* __restrict__ scW,
                                              const float* __restrict__ scb, float* __restrict__ out) {
    const int b = blockIdx.x;
    const int tid = threadIdx.x;
    __shared__ float P1[32], P2[32], feat[32], red[64];
    if (tid < 32) { P1[tid] = pool[b * 32 + tid]; P2[tid] = pool[4096 + b * 32 + tid]; }
    __syncthreads();
    const int k = tid & 15, part = tid >> 4;
    float acc = 0.f;
    for (int i = part * 8; i < part * 8 + 8; ++i) {
        float p1i = P1[i];
        for (int j = 0; j < 32; ++j) acc += p1i * P2[j] * ntnW[(i * 32 + j) * 16 + k];
    }
    red[tid] = acc;
    __syncthreads();
    if (tid < 16) {
        float bl = red[tid] + red[16 + tid] + red[32 + tid] + red[48 + tid];
        float blk = ntnb[tid];
        for (int i = 0; i < 32; ++i) blk += P1[i] * ntnV[tid * 64 + i];
        for (int j = 0; j < 32; ++j) blk += P2[j] * ntnV[tid * 64 + 32 + j];
        feat[tid] = fmaxf(bl + blk, 0.f);
        const int nn = max(cnt[b], cnt[128 + b]);
        feat[16 + tid] = hist[b * 16 + tid] / (float)(nn * nn);
    }
    __syncthreads();
    if (tid < 16) {
        float h = fc1b[tid];
        for (int f = 0; f < 32; ++f) h += feat[f] * fc1W[f * 16 + tid];
        red[tid] = fmaxf(h, 0.f);
    }
    __syncthreads();
    if (tid == 0) {
        float o = scb[0];
        for (int j = 0; j < 16; ++j) o += red[j] * scW[j];
        out[b] = 1.f / (1.f + expf(-o));
    }
}

// ---------------- launch ----------------
extern "C" void kernel_launch(void* const* d_in, const int* in_sizes, int n_in,
                              void* d_out, int out_size, void* d_ws, size_t ws_size,
                              hipStream_t stream) {
    const float* x1   = (const float*)d_in[0];
    const float* x2   = (const float*)d_in[1];
    const int*   ei1  = (const int*)d_in[2];
    const int*   ei2  = (const int*)d_in[3];
    const int*   bat1 = (const int*)d_in[4];
    const int*   bat2 = (const int*)d_in[5];
    const float* W1   = (const float*)d_in[6];
    const float* b1   = (const float*)d_in[7];
    const float* W2   = (const float*)d_in[8];
    const float* b2   = (const float*)d_in[9];
    const float* W3   = (const float*)d_in[10];
    const float* b3   = (const float*)d_in[11];
    const float* attW = (const float*)d_in[12];
    const float* ntnW = (const float*)d_in[13];
    const float* ntnV = (const float*)d_in[14];
    const float* ntnb = (const float*)d_in[15];
    const float* fc1W = (const float*)d_in[16];
    const float* fc1b = (const float*)d_in[17];
    const float* scW  = (const float*)d_in[18];
    const float* scb  = (const float*)d_in[19];
    float* out = (float*)d_out;

    // workspace layout (~70 MB)
    uint32* Hbuf   = (uint32*)d_ws;                       // hs rows: 131072*32 u32 (16.8 MB)
    uint32* Gb     = Hbuf + (size_t)TOT2 * 32;            // activations: 131072*32 u32 (16.8 MB)
    uint32* AFb    = Gb + (size_t)TOT2 * 32;              // AF: 131072*16 u32 (8.4 MB)
    uint32* bkt    = AFb + (size_t)TOT2 * 16;             // strided buckets: NB*CAP u32 (10.5 MB)
    uint32* csr    = bkt + (size_t)NB * CAP;              // CSR src lists: NB*CAP u32 (10.5 MB)
    float* dis     = (float*)(csr + (size_t)NB * CAP);    // 131072
    int*   rowstart= (int*)(dis + TOT2);                  // 131072
    int*   rowend  = rowstart + TOT2;                     // 131072
    int*   gcnt    = rowend + TOT2;                       // 1024
    int*   cnt     = gcnt + NB;                           // 256
    int*   st      = cnt + 256;                           // 256
    float* pool    = (float*)(st + 256);                  // 8192
    float* hist    = pool + 8192;                         // 2048
    float* bmn     = hist + 2048;                         // 1024
    float* bmx     = bmn + 1024;                          // 1024
    ushort16* Wt1  = (ushort16*)(bmx + 1024);             // 64*128 bf16
    ushort16* Wt2  = Wt1 + 8192;                          // 64*64
    ushort16* Wt3  = Wt2 + 4096;                          // 32*64

    hipMemsetAsync(gcnt, 0, NB * sizeof(int), stream);
    hipMemsetAsync(hist, 0, 2048 * sizeof(float), stream);
    setup_k<<<57, 256, 0, stream>>>(W1, W2, W3, Wt1, Wt2, Wt3, bat1, bat2, cnt, st);
    bktfill2_k<<<256, 256, 0, stream>>>(ei1, ei2, gcnt, bkt);
    bktsort_k<<<NB, 256, 0, stream>>>(gcnt, bkt, csr, rowstart, rowend, dis);

    // Layer 1 (K=128 f32 -> hs bf16), MFMA
    gemmf_k<128, 64, false, false><<<2048, 256, 0, stream>>>(x1, x2, Wt1, dis, (ushort16*)Hbuf);
    gatherb_k<64><<<TOT2 / 16, 256, 0, stream>>>(Gb, Hbuf, dis, b1, rowstart, rowend, csr);

    // Layer 2 (64 -> 64), relu fused into A-fragment load
    gemmf_k<64, 64, true, true><<<2048, 256, 0, stream>>>(Gb, Gb, Wt2, dis, (ushort16*)Hbuf);
    gatherb_k<64><<<TOT2 / 16, 256, 0, stream>>>(Gb, Hbuf, dis, b2, rowstart, rowend, csr);

    // Layer 3 (64 -> 32)
    gemmf_k<64, 32, true, true><<<2048, 256, 0, stream>>>(Gb, Gb, Wt3, dis, (ushort16*)Hbuf);
    gatherb_k<32><<<TOT2 / 32, 256, 0, stream>>>(AFb, Hbuf, dis, b3, rowstart, rowend, csr);

    // Pooling, histogram, head
    attpool_k<<<256, 256, 0, stream>>>((const ushort16*)AFb, cnt, st, attW, pool);
    mm2_k<<<1024, 256, 0, stream>>>((const ushort16*)AFb, cnt, st, bmn, bmx);
    bin2_k<<<1024, 256, 0, stream>>>((const ushort16*)AFb, cnt, st, bmn, bmx, hist);
    final_k<<<128, 64, 0, stream>>>(pool, hist, cnt, ntnW, ntnV, ntnb, fc1W, fc1b, scW, scb, out);
}